// Round 5
// baseline (3196.779 us; speedup 1.0000x reference)
//
#include <hip/hip_runtime.h>

#define Nn 16384
#define Ee 262144
#define Dd 128
#define DEe 64
#define Hh 256
#define KK 16
#define NSPLIT 16
#define TT 128      /* knn targets per block */
#define STILE 128   /* knn source tile */
#define SWEEP (Nn / NSPLIT)
#define PXS 136     /* bf16 source-tile pitch (ushorts) */
#define PDD 66      /* dtile pitch (floats) */
#define MCAND 32    /* rerank candidates per target */
#define BDEPTH 8    /* per-lane survivor buffer depth */
#define LDEPTH 8    /* per-parity-thread top list depth (2x8 -> merged 16/split) */

typedef __attribute__((ext_vector_type(8))) short short8;
typedef __attribute__((ext_vector_type(4))) float floatx4;

// ---------- bf16 helpers ----------
__device__ __forceinline__ ushort f2bf(float f) {
  uint u = __float_as_uint(f);
  u += 0x7fffu + ((u >> 16) & 1u);
  return (ushort)(u >> 16);
}
__device__ __forceinline__ float bf2f(ushort h) { return __uint_as_float(((uint)h) << 16); }
__device__ __forceinline__ void cvt_hilo(float4 v, uint2* hi, uint2* lo) {
  ushort h0 = f2bf(v.x), h1 = f2bf(v.y), h2 = f2bf(v.z), h3 = f2bf(v.w);
  ushort l0 = f2bf(v.x - bf2f(h0)), l1 = f2bf(v.y - bf2f(h1));
  ushort l2 = f2bf(v.z - bf2f(h2)), l3 = f2bf(v.w - bf2f(h3));
  hi->x = (uint)h0 | ((uint)h1 << 16); hi->y = (uint)h2 | ((uint)h3 << 16);
  lo->x = (uint)l0 | ((uint)l1 << 16); lo->y = (uint)l2 | ((uint)l3 << 16);
}
__device__ __forceinline__ uint4 pk8(float4 a, float4 b) {
  uint4 o;
  o.x = (uint)f2bf(a.x) | ((uint)f2bf(a.y) << 16);
  o.y = (uint)f2bf(a.z) | ((uint)f2bf(a.w) << 16);
  o.z = (uint)f2bf(b.x) | ((uint)f2bf(b.y) << 16);
  o.w = (uint)f2bf(b.z) | ((uint)f2bf(b.w) << 16);
  return o;
}

// edge_index access: mode=1 -> int32 layout, mode=0 -> int64 (low words at even positions)
__device__ __forceinline__ int ld_src(const int* ei, int e, int mode) {
  return mode ? ei[e] : ei[2 * e];
}
__device__ __forceinline__ int ld_dst(const int* ei, int e, int mode) {
  return mode ? ei[Ee + e] : ei[2 * Ee + 2 * e];
}

__global__ void k_detect(const int* __restrict__ ei, int* __restrict__ flag) {
  if (blockIdx.x == 0 && threadIdx.x == 0) {
    int any = 0;
    for (int i = 0; i < 64; ++i) any |= ei[2 * i + 1];
    *flag = (any != 0) ? 1 : 0;
  }
}

__global__ void k_hist(const int* __restrict__ ei, const int* __restrict__ mode_p,
                       int* __restrict__ hist) {
  int e = blockIdx.x * 256 + threadIdx.x;
  int mode = *mode_p;
  atomicAdd(&hist[ld_dst(ei, e, mode)], 1);
}

__global__ void k_scan(const int* __restrict__ hist, int* __restrict__ cursor) {
  __shared__ int part[256];
  __shared__ int partx[256];
  int t = threadIdx.x;
  int base = t * (Nn / 256);
  int s = 0;
  for (int i = 0; i < Nn / 256; ++i) s += hist[base + i];
  part[t] = s;
  __syncthreads();
  if (t == 0) {
    int run = 0;
    for (int i = 0; i < 256; ++i) { partx[i] = run; run += part[i]; }
  }
  __syncthreads();
  int run = partx[t];
  for (int i = 0; i < Nn / 256; ++i) { int v = hist[base + i]; cursor[base + i] = run; run += v; }
}

__global__ void k_scatter(const int* __restrict__ ei, const int* __restrict__ mode_p,
                          int* __restrict__ cursor, int* __restrict__ perm,
                          int* __restrict__ dstS) {
  int e = blockIdx.x * 256 + threadIdx.x;
  int mode = *mode_p;
  int d = ld_dst(ei, e, mode);
  int pos = atomicAdd(&cursor[d], 1);
  perm[pos] = e;
  dstS[pos] = d;
}

__global__ void k_sq(const float* __restrict__ x, float* __restrict__ sq) {
  int n = blockIdx.x * 256 + threadIdx.x;
  const float4* p = (const float4*)(x + (size_t)n * Dd);
  float acc = 0.f;
#pragma unroll
  for (int i = 0; i < Dd / 4; ++i) {
    float4 v = p[i];
    acc += v.x * v.x + v.y * v.y + v.z * v.z + v.w * v.w;
  }
  sq[n] = acc;
}

// ---- weight repack: fp32 [K][N] -> bf16 MFMA-B layout, K' = 2K (hi rows then lo rows) ----
__global__ void k_repack(const float* __restrict__ sW1, const float* __restrict__ sW2,
                         const float* __restrict__ dW1, const float* __restrict__ dW2,
                         uint4* __restrict__ out) {
  int gid = blockIdx.x * 256 + threadIdx.x;
  const float* W; int K, N, u, obase;
  if (gid < 36864) {
    int i = gid / 12288; u = gid - i * 12288;
    W = sW1 + (size_t)i * 49152; K = 192; N = 256; obase = i * 12288;
  } else if (gid < 61440) {
    int g = gid - 36864; int i = g / 8192; u = g - i * 8192;
    W = sW2 + (size_t)i * 32768; K = 256; N = 128; obase = 36864 + i * 8192;
  } else if (gid < 94208) {
    int g = gid - 61440; int i = g / 16384; u = g - i * 16384;
    W = dW1 + (size_t)i * 65536; K = 256; N = 256; obase = 61440 + i * 16384;
  } else if (gid < 110592) {
    int g = gid - 94208; int i = g / 8192; u = g - i * 8192;
    W = dW2 + (size_t)i * 32768; K = 256; N = 128; obase = 94208 + i * 8192;
  } else return;
  int lane = u & 63;
  int t = u >> 6;
  int ksteps = K / 16;
  int kstep = t % ksteps, ntile = t / ksteps;
  int R = K / 32;
  bool lo = kstep >= R;
  int k0 = (lo ? kstep - R : kstep) * 32 + (lane >> 4) * 8;
  int n = ntile * 16 + (lane & 15);
  ushort v[8];
#pragma unroll
  for (int j = 0; j < 8; ++j) {
    float w = W[(size_t)(k0 + j) * N + n];
    ushort h = f2bf(w);
    v[j] = lo ? f2bf(w - bf2f(h)) : h;
  }
  uint4 o;
  o.x = (uint)v[0] | ((uint)v[1] << 16);
  o.y = (uint)v[2] | ((uint)v[3] << 16);
  o.z = (uint)v[4] | ((uint)v[5] << 16);
  o.w = (uint)v[6] | ((uint)v[7] << 16);
  out[obase + u] = o;
}

// ---- bf16x3 MFMA GEMM core for MLPs ----
template <int RK, int NT>
__device__ __forceinline__ void mfma3(const ushort* aB, int pitch, const uint4* __restrict__ Wp,
                                      int lane, floatx4 C[2][NT]) {
  int q = lane >> 4, m0 = lane & 15;
  short8 ahc[RK][2];
#pragma unroll
  for (int hm = 0; hm < 2; ++hm)
#pragma unroll
    for (int nt = 0; nt < NT; ++nt)
#pragma unroll
      for (int rr = 0; rr < 4; ++rr) C[hm][nt][rr] = 0.f;
#pragma unroll
  for (int s = 0; s < RK; ++s) {
    short8 ah0 = *(const short8*)(aB + m0 * pitch + s * 32 + q * 8);
    short8 ah1 = *(const short8*)(aB + (m0 + 16) * pitch + s * 32 + q * 8);
    short8 al0 = *(const short8*)(aB + m0 * pitch + (RK + s) * 32 + q * 8);
    short8 al1 = *(const short8*)(aB + (m0 + 16) * pitch + (RK + s) * 32 + q * 8);
    ahc[s][0] = ah0;
    ahc[s][1] = ah1;
#pragma unroll
    for (int nt = 0; nt < NT; ++nt) {
      uint4 bw = Wp[(nt * 2 * RK + s) * 64 + lane];
      short8 b = *(short8*)&bw;
      C[0][nt] = __builtin_amdgcn_mfma_f32_16x16x32_bf16(ah0, b, C[0][nt], 0, 0, 0);
      C[1][nt] = __builtin_amdgcn_mfma_f32_16x16x32_bf16(ah1, b, C[1][nt], 0, 0, 0);
      C[0][nt] = __builtin_amdgcn_mfma_f32_16x16x32_bf16(al0, b, C[0][nt], 0, 0, 0);
      C[1][nt] = __builtin_amdgcn_mfma_f32_16x16x32_bf16(al1, b, C[1][nt], 0, 0, 0);
    }
  }
#pragma unroll
  for (int s = 0; s < RK; ++s) {
#pragma unroll
    for (int nt = 0; nt < NT; ++nt) {
      uint4 bw = Wp[(nt * 2 * RK + RK + s) * 64 + lane];
      short8 b = *(short8*)&bw;
      C[0][nt] = __builtin_amdgcn_mfma_f32_16x16x32_bf16(ahc[s][0], b, C[0][nt], 0, 0, 0);
      C[1][nt] = __builtin_amdgcn_mfma_f32_16x16x32_bf16(ahc[s][1], b, C[1][nt], 0, 0, 0);
    }
  }
}

// ---- kNN prefilter: bf16 MFMA dots, writer-side distances, col-only survivor buffer ----
__global__ __launch_bounds__(256, 4) void k_knn_part(const float* __restrict__ x,
                                                     const float* __restrict__ sq,
                                                     float* __restrict__ part_d,
                                                     int* __restrict__ part_i) {
  __shared__ __align__(16) ushort smXS[128 * PXS];  // bf16 src tile / fp32 dtile / merge bufs
  __shared__ float sqs_l[STILE];
  __shared__ ushort smBuf[BDEPTH * 256];  // survivor col buffer, [p][tid]
  float* dtile = (float*)smXS;            // [128][PDD], holds full distances d
  float* mbD = (float*)smXS;              // merge: 256*LDEPTH floats
  int* mbI = ((int*)smXS) + 2048;
  int tid = threadIdx.x;
  int wave = tid >> 6, lane = tid & 63;
  int quad = lane >> 4, n15 = lane & 15;
  int tileT = blockIdx.x >> 4;
  int split = blockIdx.x & 15;
  int tb = tileT * TT;
  int tg = tid >> 1, sl = tid & 1;

  // per-lane C-row target sq (8 output rows: mt in {0,1}, rr in 0..3)
  float sqi8[8];
#pragma unroll
  for (int mt = 0; mt < 2; ++mt)
#pragma unroll
    for (int rr = 0; rr < 4; ++rr)
      sqi8[mt * 4 + rr] = sq[tb + wave * 32 + mt * 16 + quad * 4 + rr];

  // A-fragments in registers (targets fixed for whole block)
  short8 afr[2][4];
#pragma unroll
  for (int mt = 0; mt < 2; ++mt) {
    int row = tb + wave * 32 + mt * 16 + n15;
#pragma unroll
    for (int ks = 0; ks < 4; ++ks) {
      int k0 = ks * 32 + quad * 8;
      float4 a = *(const float4*)&x[(size_t)row * Dd + k0];
      float4 b = *(const float4*)&x[(size_t)row * Dd + k0 + 4];
      uint4 p = pk8(a, b);
      afr[mt][ks] = *(short8*)&p;
    }
  }

  float bd[LDEPTH];
  int bi[LDEPTH];
#pragma unroll
  for (int p2 = 0; p2 < LDEPTH; ++p2) { bd[p2] = 3.0e38f; bi[p2] = 0x7fffffff; }
  int bcnt = 0;

  // exact depth-8 predicated sorted insert
  auto ins = [&](float d, int gidx) {
#pragma unroll
    for (int p = LDEPTH - 1; p >= 1; --p) {
      bool shift = d < bd[p - 1];
      bool here = (!shift) && (d < bd[p]);
      float nb = shift ? bd[p - 1] : (here ? d : bd[p]);
      int ni = shift ? bi[p - 1] : (here ? gidx : bi[p]);
      bd[p] = nb;
      bi[p] = ni;
    }
    if (d < bd[0]) { bd[0] = d; bi[0] = gidx; }
  };

#pragma unroll 1
  for (int st = 0; st < SWEEP / STILE; ++st) {
    int sb = split * SWEEP + st * STILE;
    __syncthreads();  // prior dtile/merge use of smXS done
    {
      int row = tid & 127, kh = (tid >> 7) * 64;
      int swz = ((row >> 3) & 7) << 3;
#pragma unroll
      for (int g = 0; g < 8; ++g) {
        int k0 = kh + g * 8;
        float4 a = *(const float4*)&x[(size_t)(sb + row) * Dd + k0];
        float4 b = *(const float4*)&x[(size_t)(sb + row) * Dd + k0 + 4];
        *(uint4*)&smXS[row * PXS + (k0 ^ swz)] = pk8(a, b);
      }
      if (tid < STILE) sqs_l[tid] = sq[sb + tid];
    }
    __syncthreads();
    floatx4 C[2][8];
#pragma unroll
    for (int mt = 0; mt < 2; ++mt)
#pragma unroll
      for (int nt = 0; nt < 8; ++nt)
#pragma unroll
        for (int rr = 0; rr < 4; ++rr) C[mt][nt][rr] = 0.f;
#pragma unroll
    for (int nt = 0; nt < 8; ++nt) {
      int s = nt * 16 + n15;
      int swz = ((s >> 3) & 7) << 3;
#pragma unroll
      for (int ks = 0; ks < 4; ++ks) {
        int k0 = ks * 32 + quad * 8;
        short8 bfr = *(const short8*)&smXS[s * PXS + (k0 ^ swz)];
        C[0][nt] = __builtin_amdgcn_mfma_f32_16x16x32_bf16(afr[0][ks], bfr, C[0][nt], 0, 0, 0);
        C[1][nt] = __builtin_amdgcn_mfma_f32_16x16x32_bf16(afr[1][ks], bfr, C[1][nt], 0, 0, 0);
      }
    }
    // source sq for this tile (both halves): col (nt*16+n15) in 0..127
    float sc[8];
#pragma unroll
    for (int nt = 0; nt < 8; ++nt) sc[nt] = sqs_l[nt * 16 + n15];
    __syncthreads();  // xs reads done -> alias as dtile
#pragma unroll
    for (int h = 0; h < 2; ++h) {
      if (h) __syncthreads();
      // writer computes full distance d = -2*dot + sq_i + sq_j
#pragma unroll
      for (int mt = 0; mt < 2; ++mt)
#pragma unroll
        for (int nt = 0; nt < 4; ++nt)
#pragma unroll
          for (int rr = 0; rr < 4; ++rr) {
            int row = wave * 32 + mt * 16 + quad * 4 + rr;
            int col = nt * 16 + n15;
            float d = fmaf(-2.f, C[mt][nt + 4 * h][rr], sqi8[mt * 4 + rr]) + sc[nt + 4 * h];
            dtile[row * PDD + col] = d;
          }
      __syncthreads();
      const float* drow = &dtile[tg * PDD];
#pragma unroll 1
      for (int j = 0; j < 32; ++j) {
        int col = sl + 2 * j;
        float d = drow[col];
        if (d < bd[LDEPTH - 1]) {
          if (bcnt < BDEPTH) {
            smBuf[bcnt * 256 + tid] = (ushort)col;
            ++bcnt;
          } else {
            ins(d, sb + h * 64 + col);  // overflow fallback (frequent only in early tiles)
          }
        }
      }
      // per-half flush while dtile is valid: re-read d by stored column
#pragma unroll 1
      for (int p = 0; p < BDEPTH; ++p) {
        bool act = p < bcnt;
        if (!__any(act)) break;
        if (act) {
          int col = smBuf[p * 256 + tid];
          float d = drow[col];
          ins(d, sb + h * 64 + col);
        }
      }
      bcnt = 0;
    }
  }

  // block-end: merge the two parity depth-8 lists per target -> sorted 16 per (target, split)
  __syncthreads();
#pragma unroll
  for (int o = 0; o < LDEPTH; ++o) {
    mbD[tid * LDEPTH + o] = bd[o];
    mbI[tid * LDEPTH + o] = bi[o];
  }
  __syncthreads();
  if (tid < TT) {
    const float* la = &mbD[(2 * tid) * LDEPTH];
    const float* lb = &mbD[(2 * tid + 1) * LDEPTH];
    const int* ia = &mbI[(2 * tid) * LDEPTH];
    const int* ib = &mbI[(2 * tid + 1) * LDEPTH];
    int pa = 0, pb = 0;
    size_t base = ((size_t)(tb + tid) * NSPLIT + split) * KK;
#pragma unroll
    for (int o = 0; o < KK; ++o) {
      float da = (pa < LDEPTH) ? la[pa] : 3.4e38f;
      float db = (pb < LDEPTH) ? lb[pb] : 3.4e38f;
      int iaa = (pa < LDEPTH) ? ia[pa] : 0x7fffffff;
      int ibb = (pb < LDEPTH) ? ib[pb] : 0x7fffffff;
      bool pick = (da < db) || (da == db && iaa < ibb);
      part_d[base + o] = pick ? da : db;
      part_i[base + o] = pick ? iaa : ibb;
      pa += pick ? 1 : 0;
      pb += pick ? 0 : 1;
    }
  }
}

// merge split lists -> approx top-32 candidate indices per target
__global__ void k_knn_merge(const float* __restrict__ part_d, const int* __restrict__ part_i,
                            int* __restrict__ cand) {
  int n = blockIdx.x * 256 + threadIdx.x;
  const float* pd = part_d + (size_t)n * NSPLIT * KK;
  const int* pi = part_i + (size_t)n * NSPLIT * KK;
  int pos[NSPLIT];
#pragma unroll
  for (int l = 0; l < NSPLIT; ++l) pos[l] = 0;
  for (int o = 0; o < MCAND; ++o) {
    float bestd = 3.3e38f;
    int besti = 0x7fffffff;
    int bestl = 0;
#pragma unroll
    for (int l = 0; l < NSPLIT; ++l) {
      if (pos[l] < KK) {
        float dd = pd[l * KK + pos[l]];
        int ii = pi[l * KK + pos[l]];
        if (dd < bestd || (dd == bestd && ii < besti)) { bestd = dd; besti = ii; bestl = l; }
      }
    }
    cand[(size_t)n * MCAND + o] = besti;
#pragma unroll
    for (int l = 0; l < NSPLIT; ++l) pos[l] += (l == bestl) ? 1 : 0;
  }
}

// exact fp32 rerank of 32 candidates -> ordered top-16 (same math/ties as full fp32 scan)
__global__ __launch_bounds__(256) void k_rerank(const float* __restrict__ x,
                                                const float* __restrict__ sq,
                                                const int* __restrict__ cand,
                                                int* __restrict__ knn_src) {
  int tid = threadIdx.x;
  int wave = tid >> 6, lane = tid & 63;
  int t = blockIdx.x * 4 + wave;
  int c = lane & 31, h = lane >> 5;
  int idx = cand[(size_t)t * MCAND + c];
  const float* xt = x + (size_t)t * Dd + h * 64;
  const float* xc = x + (size_t)idx * Dd + h * 64;
  float s = 0.f;
#pragma unroll
  for (int g = 0; g < 16; ++g) {
    float4 a = *(const float4*)&xt[g * 4];
    float4 b = *(const float4*)&xc[g * 4];
    s += a.x * b.x + a.y * b.y + a.z * b.z + a.w * b.w;
  }
  s += __shfl_xor(s, 32);
  float d = fmaf(-2.f, s, sq[t]) + sq[idx];
  int rank = 0;
#pragma unroll
  for (int j = 0; j < 32; ++j) {
    float dj = __shfl(d, j);
    int ij = __shfl(idx, j);
    rank += ((dj < d) || (dj == d && ij < idx)) ? 1 : 0;
  }
  if (lane < 32 && rank < KK) knn_src[t * KK + rank] = idx;
}

// ---------------- static message MLP (bf16x3 MFMA) + grouped scatter-add ----------------
__global__ __launch_bounds__(256, 3) void k_static_msg(
    const float* __restrict__ xs, const float* __restrict__ ea, const int* __restrict__ ei,
    const int* __restrict__ mode_p, const int* __restrict__ perm, const int* __restrict__ dstS,
    const uint4* __restrict__ W1p, const float* __restrict__ b1,
    const uint4* __restrict__ W2p, const float* __restrict__ b2, float* __restrict__ agg) {
  __shared__ __align__(16) ushort smH[32 * 520];
  __shared__ int dstLoc[32];
  int tid = threadIdx.x;
  int wave = tid >> 6, lane = tid & 63;
  int pb = blockIdx.x * 32;
  int mode = *mode_p;
  int r = tid & 31, q8 = tid >> 5;
  int p = pb + r;
  int e = perm[p];
  int ds = dstS[p];
  int sr = ld_src(ei, e, mode);
  if (q8 == 0) dstLoc[r] = ds;
  const float* eap = ea + (size_t)e * DEe;
  const float* xsp = xs + (size_t)sr * Dd;
  const float* xdp = xs + (size_t)ds * Dd;
#pragma unroll
  for (int it = 0; it < 6; ++it) {
    int f = q8 * 24 + it * 4;
    float4 v;
    if (f < 64) {
      v = *(const float4*)&eap[f];
    } else {
      float4 a = *(const float4*)&xsp[f - 64];
      float4 b = *(const float4*)&xdp[f - 64];
      v = make_float4(a.x - b.x, a.y - b.y, a.z - b.z, a.w - b.w);
    }
    uint2 hi, lo;
    cvt_hilo(v, &hi, &lo);
    *(uint2*)&smH[r * 392 + f] = hi;
    *(uint2*)&smH[r * 392 + 192 + f] = lo;
  }
  __syncthreads();
  floatx4 C1[2][4];
  mfma3<6, 4>(smH, 392, W1p + (size_t)wave * 4 * 12 * 64, lane, C1);
  __syncthreads();
  {
    int q = lane >> 4, n15 = lane & 15;
#pragma unroll
    for (int hm = 0; hm < 2; ++hm)
#pragma unroll
      for (int nt = 0; nt < 4; ++nt) {
        int n = wave * 64 + nt * 16 + n15;
        float bv = b1[n];
#pragma unroll
        for (int rr = 0; rr < 4; ++rr) {
          int m = hm * 16 + q * 4 + rr;
          float h = fmaxf(C1[hm][nt][rr] + bv, 0.f);
          ushort hh = f2bf(h);
          smH[m * 520 + n] = hh;
          smH[m * 520 + 256 + n] = f2bf(h - bf2f(hh));
        }
      }
  }
  __syncthreads();
  floatx4 C2[2][2];
  mfma3<8, 2>(smH, 520, W2p + (size_t)wave * 2 * 16 * 64, lane, C2);
  __syncthreads();
  float* smM = (float*)smH;
  {
    int q = lane >> 4, n15 = lane & 15;
#pragma unroll
    for (int hm = 0; hm < 2; ++hm)
#pragma unroll
      for (int nt = 0; nt < 2; ++nt) {
        int n = wave * 32 + nt * 16 + n15;
        float bv = b2[n];
#pragma unroll
        for (int rr = 0; rr < 4; ++rr) {
          int m = hm * 16 + q * 4 + rr;
          smM[m * 132 + n] = fmaxf(C2[hm][nt][rr] + bv, 0.f);
        }
      }
  }
  __syncthreads();
  int col = tid & 127, half = tid >> 7;
  int r0 = half * 16;
  float run = smM[r0 * 132 + col];
  int prevd = dstLoc[r0];
  for (int rr = 1; rr < 16; ++rr) {
    int row = r0 + rr;
    int dd2 = dstLoc[row];
    float v = smM[row * 132 + col];
    if (dd2 != prevd) {
      atomicAdd(&agg[(size_t)prevd * Dd + col], run);
      run = v;
      prevd = dd2;
    } else {
      run += v;
    }
  }
  atomicAdd(&agg[(size_t)prevd * Dd + col], run);
}

// ---------------- dynamic (kNN) message MLP (bf16x3 MFMA), atomic-free ----------------
__global__ __launch_bounds__(256, 3) void k_dyn_msg(
    const float* __restrict__ xd, const int* __restrict__ knn, const uint4* __restrict__ W1p,
    const float* __restrict__ b1, const uint4* __restrict__ W2p, const float* __restrict__ b2,
    float* __restrict__ agg) {
  __shared__ __align__(16) ushort smH[32 * 520];
  int tid = threadIdx.x;
  int wave = tid >> 6, lane = tid & 63;
  int nb2 = blockIdx.x * 2;
  int r = tid & 31, q8 = tid >> 5;
  int tgt = nb2 + (r >> 4);
  int nj = knn[tgt * KK + (r & 15)];
  const float* xip = xd + (size_t)tgt * Dd;
  const float* xjp = xd + (size_t)nj * Dd;
#pragma unroll
  for (int it = 0; it < 8; ++it) {
    int f = q8 * 32 + it * 4;
    float4 v;
    if (f < 128) {
      v = *(const float4*)&xip[f];
    } else {
      float4 a = *(const float4*)&xjp[f - 128];
      float4 b = *(const float4*)&xip[f - 128];
      v = make_float4(a.x - b.x, a.y - b.y, a.z - b.z, a.w - b.w);
    }
    uint2 hi, lo;
    cvt_hilo(v, &hi, &lo);
    *(uint2*)&smH[r * 520 + f] = hi;
    *(uint2*)&smH[r * 520 + 256 + f] = lo;
  }
  __syncthreads();
  floatx4 C1[2][4];
  mfma3<8, 4>(smH, 520, W1p + (size_t)wave * 4 * 16 * 64, lane, C1);
  __syncthreads();
  {
    int q = lane >> 4, n15 = lane & 15;
#pragma unroll
    for (int hm = 0; hm < 2; ++hm)
#pragma unroll
      for (int nt = 0; nt < 4; ++nt) {
        int n = wave * 64 + nt * 16 + n15;
        float bv = b1[n];
#pragma unroll
        for (int rr = 0; rr < 4; ++rr) {
          int m = hm * 16 + q * 4 + rr;
          float h = fmaxf(C1[hm][nt][rr] + bv, 0.f);
          ushort hh = f2bf(h);
          smH[m * 520 + n] = hh;
          smH[m * 520 + 256 + n] = f2bf(h - bf2f(hh));
        }
      }
  }
  __syncthreads();
  floatx4 C2[2][2];
  mfma3<8, 2>(smH, 520, W2p + (size_t)wave * 2 * 16 * 64, lane, C2);
  int q = lane >> 4, n15 = lane & 15;
#pragma unroll
  for (int hm = 0; hm < 2; ++hm)
#pragma unroll
    for (int nt = 0; nt < 2; ++nt) {
      int n = wave * 32 + nt * 16 + n15;
      float bv = b2[n];
      float s = 0.f;
#pragma unroll
      for (int rr = 0; rr < 4; ++rr) s += fmaxf(C2[hm][nt][rr] + bv, 0.f);
      s += __shfl_xor(s, 16);
      s += __shfl_xor(s, 32);
      if (q == 0) agg[(size_t)(nb2 + hm) * Dd + n] = s;
    }
}

// ---------------- fp32 fused 2-layer MLP core (node update / fuse) ----------------
__device__ __forceinline__ void mlp_l1(int tid, int indim, const float* __restrict__ W1,
                                       const float* __restrict__ b1, float* smA, float* smB) {
  int rg = tid >> 5, cg = tid & 31;
  float acc[32];
#pragma unroll
  for (int i = 0; i < 32; ++i) acc[i] = 0.f;
  for (int kc = 0; kc < indim / 8; ++kc) {
    const float* W1g = W1 + (size_t)kc * 8 * Hh;
    *(float4*)&smB[tid * 4] = *(const float4*)&W1g[tid * 4];
    *(float4*)&smB[1024 + tid * 4] = *(const float4*)&W1g[1024 + tid * 4];
    __syncthreads();
#pragma unroll
    for (int k = 0; k < 8; ++k) {
      int kk = kc * 8 + k;
      float4 a0 = *(const float4*)&smA[kk * 32 + rg * 4];
      float4 b0 = *(const float4*)&smB[k * Hh + cg * 8];
      float4 b1v = *(const float4*)&smB[k * Hh + cg * 8 + 4];
      float av[4] = {a0.x, a0.y, a0.z, a0.w};
      float bv[8] = {b0.x, b0.y, b0.z, b0.w, b1v.x, b1v.y, b1v.z, b1v.w};
#pragma unroll
      for (int rr = 0; rr < 4; ++rr)
#pragma unroll
        for (int cc = 0; cc < 8; ++cc) acc[rr * 8 + cc] += av[rr] * bv[cc];
    }
    __syncthreads();
  }
  float4 bb0 = *(const float4*)&b1[cg * 8];
  float4 bb1 = *(const float4*)&b1[cg * 8 + 4];
  float bs[8] = {bb0.x, bb0.y, bb0.z, bb0.w, bb1.x, bb1.y, bb1.z, bb1.w};
#pragma unroll
  for (int rr = 0; rr < 4; ++rr) {
    int row = rg * 4 + rr;
    float4 h0, h1;
    h0.x = fmaxf(acc[rr * 8 + 0] + bs[0], 0.f);
    h0.y = fmaxf(acc[rr * 8 + 1] + bs[1], 0.f);
    h0.z = fmaxf(acc[rr * 8 + 2] + bs[2], 0.f);
    h0.w = fmaxf(acc[rr * 8 + 3] + bs[3], 0.f);
    h1.x = fmaxf(acc[rr * 8 + 4] + bs[4], 0.f);
    h1.y = fmaxf(acc[rr * 8 + 5] + bs[5], 0.f);
    h1.z = fmaxf(acc[rr * 8 + 6] + bs[6], 0.f);
    h1.w = fmaxf(acc[rr * 8 + 7] + bs[7], 0.f);
    *(float4*)&smA[row * 260 + cg * 8] = h0;
    *(float4*)&smA[row * 260 + cg * 8 + 4] = h1;
  }
  __syncthreads();
}

__device__ __forceinline__ void mlp_l2(int tid, const float* __restrict__ W2,
                                       const float* smA, float* smB, float acc2[16]) {
  int rg2 = tid >> 5, cg2 = tid & 31;
#pragma unroll
  for (int i = 0; i < 16; ++i) acc2[i] = 0.f;
  for (int kc = 0; kc < Hh / 16; ++kc) {
    const float* W2g = W2 + (size_t)kc * 16 * Dd;
    *(float4*)&smB[tid * 4] = *(const float4*)&W2g[tid * 4];
    *(float4*)&smB[1024 + tid * 4] = *(const float4*)&W2g[1024 + tid * 4];
    __syncthreads();
#pragma unroll
    for (int k = 0; k < 16; ++k) {
      int kk = kc * 16 + k;
      float4 b0 = *(const float4*)&smB[k * Dd + cg2 * 4];
#pragma unroll
      for (int rr = 0; rr < 4; ++rr) {
        float a = smA[(rg2 * 4 + rr) * 260 + kk];
        acc2[rr * 4 + 0] += a * b0.x;
        acc2[rr * 4 + 1] += a * b0.y;
        acc2[rr * 4 + 2] += a * b0.z;
        acc2[rr * 4 + 3] += a * b0.w;
      }
    }
    __syncthreads();
  }
}

__global__ __launch_bounds__(256, 3) void k_node_mlp2(
    const float* __restrict__ in1, const float* __restrict__ in2, int indim,
    const float* __restrict__ W1, const float* __restrict__ b1, const float* __restrict__ W2,
    const float* __restrict__ b2, float* __restrict__ out) {
  __shared__ float smA[32 * 260];
  __shared__ float smB[2048];
  int tid = threadIdx.x;
  int nb = blockIdx.x * 32;
  int r = tid & 31, q = tid >> 5;
  for (int pass = 0; pass < indim / 32; ++pass) {
    int k0 = pass * 32 + q * 4;
    float4 v;
    if (k0 < Dd)
      v = *(const float4*)&in1[(size_t)(nb + r) * Dd + k0];
    else
      v = *(const float4*)&in2[(size_t)(nb + r) * Dd + (k0 - Dd)];
    smA[(k0 + 0) * 32 + r] = v.x;
    smA[(k0 + 1) * 32 + r] = v.y;
    smA[(k0 + 2) * 32 + r] = v.z;
    smA[(k0 + 3) * 32 + r] = v.w;
  }
  __syncthreads();
  mlp_l1(tid, indim, W1, b1, smA, smB);
  float acc2[16];
  mlp_l2(tid, W2, smA, smB, acc2);
  int rg2 = tid >> 5, cg2 = tid & 31;
  float4 ob = *(const float4*)&b2[cg2 * 4];
#pragma unroll
  for (int rr = 0; rr < 4; ++rr) {
    float4 o;
    o.x = fmaxf(acc2[rr * 4 + 0] + ob.x, 0.f);
    o.y = fmaxf(acc2[rr * 4 + 1] + ob.y, 0.f);
    o.z = fmaxf(acc2[rr * 4 + 2] + ob.z, 0.f);
    o.w = fmaxf(acc2[rr * 4 + 3] + ob.w, 0.f);
    *(float4*)&out[(size_t)(nb + rg2 * 4 + rr) * Dd + cg2 * 4] = o;
  }
}

__global__ __launch_bounds__(256) void k_refine(const float* __restrict__ ein,
                                                const float* __restrict__ rW,
                                                const float* __restrict__ rb,
                                                float* __restrict__ eout) {
  __shared__ float lea[16 * 64];
  __shared__ float ldsW[64 * 64];
  int tid = threadIdx.x;
  int eb = blockIdx.x * 16;
  *(float4*)&lea[tid * 4] = *(const float4*)&ein[(size_t)eb * DEe + tid * 4];
#pragma unroll
  for (int m = 0; m < 4; ++m) {
    int i4 = tid + m * 256;
    *(float4*)&ldsW[i4 * 4] = *(const float4*)&rW[i4 * 4];
  }
  __syncthreads();
  int j = tid & 63, eg = tid >> 6;
  float bias = rb[j];
  float acc0 = 0.f, acc1 = 0.f, acc2 = 0.f, acc3 = 0.f;
#pragma unroll 8
  for (int k = 0; k < 64; ++k) {
    float w = ldsW[k * 64 + j];
    acc0 += lea[(eg + 0) * 64 + k] * w;
    acc1 += lea[(eg + 4) * 64 + k] * w;
    acc2 += lea[(eg + 8) * 64 + k] * w;
    acc3 += lea[(eg + 12) * 64 + k] * w;
  }
  eout[(size_t)(eb + eg + 0) * DEe + j] = fmaxf(acc0 + bias, 0.f);
  eout[(size_t)(eb + eg + 4) * DEe + j] = fmaxf(acc1 + bias, 0.f);
  eout[(size_t)(eb + eg + 8) * DEe + j] = fmaxf(acc2 + bias, 0.f);
  eout[(size_t)(eb + eg + 12) * DEe + j] = fmaxf(acc3 + bias, 0.f);
}

extern "C" void kernel_launch(void* const* d_in, const int* in_sizes, int n_in, void* d_out,
                              int out_size, void* d_ws, size_t ws_size, hipStream_t stream) {
  (void)in_sizes; (void)n_in; (void)out_size; (void)ws_size;
  const float* x = (const float*)d_in[0];
  const float* edge_attr = (const float*)d_in[1];
  const float* sW1 = (const float*)d_in[2];
  const float* sb1 = (const float*)d_in[3];
  const float* sW2 = (const float*)d_in[4];
  const float* sb2 = (const float*)d_in[5];
  const float* uW1 = (const float*)d_in[6];
  const float* ub1 = (const float*)d_in[7];
  const float* uW2 = (const float*)d_in[8];
  const float* ub2 = (const float*)d_in[9];
  const float* rW = (const float*)d_in[10];
  const float* rb = (const float*)d_in[11];
  const float* dW1 = (const float*)d_in[12];
  const float* db1 = (const float*)d_in[13];
  const float* dW2 = (const float*)d_in[14];
  const float* db2 = (const float*)d_in[15];
  const float* dUW1 = (const float*)d_in[16];
  const float* dUb1 = (const float*)d_in[17];
  const float* dUW2 = (const float*)d_in[18];
  const float* dUb2 = (const float*)d_in[19];
  const float* fW1 = (const float*)d_in[20];
  const float* fb1 = (const float*)d_in[21];
  const float* fW2 = (const float*)d_in[22];
  const float* fb2 = (const float*)d_in[23];
  const int* ei = (const int*)d_in[24];
  float* out = (float*)d_out;

  float* wsf = (float*)d_ws;
  size_t off = 0;
  float* ea_ws = wsf + off; off += (size_t)Ee * DEe;
  float* xs_ws = wsf + off; off += (size_t)Nn * Dd;
  float* xd_ws = wsf + off; off += (size_t)Nn * Dd;
  float* agg = wsf + off;   off += (size_t)Nn * Dd;
  float* sq = wsf + off;    off += Nn;
  int* knn_src = (int*)(wsf + off); off += (size_t)Nn * KK;
  int* hist = (int*)(wsf + off);   off += Nn;
  int* cursor = (int*)(wsf + off); off += Nn;
  int* perm = (int*)(wsf + off);   off += Ee;
  int* dstS = (int*)(wsf + off);   off += Ee;
  int* modep = (int*)(wsf + off);  off += 1;
  off = (off + 3) & ~(size_t)3;  // 16B align for uint4
  uint4* wpk = (uint4*)(wsf + off); off += (size_t)110592 * 4;
  // kNN scratch overlaps ea_ws (edge_attr refinement dead before dynamic branch)
  float* part_d = ea_ws;
  int* part_i = (int*)(ea_ws + (size_t)Nn * NSPLIT * KK);
  int* cand = (int*)(ea_ws + 2 * (size_t)Nn * NSPLIT * KK);

  // edge_index probe + counting sort by dst
  k_detect<<<1, 64, 0, stream>>>(ei, modep);
  hipMemsetAsync(hist, 0, Nn * sizeof(int), stream);
  k_hist<<<Ee / 256, 256, 0, stream>>>(ei, modep, hist);
  k_scan<<<1, 256, 0, stream>>>(hist, cursor);
  k_scatter<<<Ee / 256, 256, 0, stream>>>(ei, modep, cursor, perm, dstS);

  // repack all msg-MLP weights into bf16 hi/lo MFMA-B layout
  k_repack<<<432, 256, 0, stream>>>(sW1, sW2, dW1, dW2, wpk);

  // ---- static branch: 3 convs + 2 refiners ----
  const float* xs_cur = x;
  const float* ea_cur = edge_attr;
  for (int i = 0; i < 3; ++i) {
    hipMemsetAsync(agg, 0, (size_t)Nn * Dd * sizeof(float), stream);
    k_static_msg<<<Ee / 32, 256, 0, stream>>>(
        xs_cur, ea_cur, ei, modep, perm, dstS, wpk + (size_t)i * 12288,
        sb1 + (size_t)i * Hh, wpk + 36864 + (size_t)i * 8192, sb2 + (size_t)i * Dd, agg);
    k_node_mlp2<<<Nn / 32, 256, 0, stream>>>(
        agg, (const float*)nullptr, Dd, uW1 + (size_t)i * Dd * Hh, ub1 + (size_t)i * Hh,
        uW2 + (size_t)i * Hh * Dd, ub2 + (size_t)i * Dd, xs_ws);
    xs_cur = xs_ws;
    if (i < 2) {
      k_refine<<<Ee / 16, 256, 0, stream>>>(ea_cur, rW + (size_t)i * DEe * DEe,
                                            rb + (size_t)i * DEe, ea_ws);
      ea_cur = ea_ws;
    }
  }

  // ---- dynamic branch: 2 kNN convs (MFMA prefilter -> merge32 -> exact rerank) ----
  const float* xd_cur = x;
  for (int i = 0; i < 2; ++i) {
    k_sq<<<Nn / 256, 256, 0, stream>>>(xd_cur, sq);
    k_knn_part<<<(Nn / TT) * NSPLIT, 256, 0, stream>>>(xd_cur, sq, part_d, part_i);
    k_knn_merge<<<Nn / 256, 256, 0, stream>>>(part_d, part_i, cand);
    k_rerank<<<Nn / 4, 256, 0, stream>>>(xd_cur, sq, cand, knn_src);
    k_dyn_msg<<<Nn / 2, 256, 0, stream>>>(
        xd_cur, knn_src, wpk + 61440 + (size_t)i * 16384, db1 + (size_t)i * Hh,
        wpk + 94208 + (size_t)i * 8192, db2 + (size_t)i * Dd, agg);
    k_node_mlp2<<<Nn / 32, 256, 0, stream>>>(
        agg, (const float*)nullptr, Dd, dUW1 + (size_t)i * Dd * Hh, dUb1 + (size_t)i * Hh,
        dUW2 + (size_t)i * Hh * Dd, dUb2 + (size_t)i * Dd, xd_ws);
    xd_cur = xd_ws;
  }

  // ---- fuse MLP ----
  k_node_mlp2<<<Nn / 32, 256, 0, stream>>>(xs_ws, xd_ws, 2 * Dd, fW1, fb1, fW2, fb2, out);
}

// Round 6
// 2977.288 us; speedup vs baseline: 1.0737x; 1.0737x over previous
//
#include <hip/hip_runtime.h>

#define Nn 16384
#define Ee 262144
#define Dd 128
#define DEe 64
#define Hh 256
#define KK 16
#define NSPLIT 16
#define TT 128      /* knn targets per block */
#define STILE 128   /* knn source tile */
#define SWEEP (Nn / NSPLIT)
#define PXS 136     /* bf16 source-tile pitch (ushorts) */
#define PDD 66      /* dtile pitch (floats) */
#define MCAND 32    /* rerank candidates per target */
#define BDEPTH 8    /* per-lane survivor buffer depth */
#define LDEPTH 8    /* per-parity-thread top list depth (2x8 -> merged 16/split) */

typedef __attribute__((ext_vector_type(8))) short short8;
typedef __attribute__((ext_vector_type(4))) float floatx4;

// ---------- bf16 helpers ----------
__device__ __forceinline__ ushort f2bf(float f) {
  uint u = __float_as_uint(f);
  u += 0x7fffu + ((u >> 16) & 1u);
  return (ushort)(u >> 16);
}
__device__ __forceinline__ float bf2f(ushort h) { return __uint_as_float(((uint)h) << 16); }
__device__ __forceinline__ void cvt_hilo(float4 v, uint2* hi, uint2* lo) {
  ushort h0 = f2bf(v.x), h1 = f2bf(v.y), h2 = f2bf(v.z), h3 = f2bf(v.w);
  ushort l0 = f2bf(v.x - bf2f(h0)), l1 = f2bf(v.y - bf2f(h1));
  ushort l2 = f2bf(v.z - bf2f(h2)), l3 = f2bf(v.w - bf2f(h3));
  hi->x = (uint)h0 | ((uint)h1 << 16); hi->y = (uint)h2 | ((uint)h3 << 16);
  lo->x = (uint)l0 | ((uint)l1 << 16); lo->y = (uint)l2 | ((uint)l3 << 16);
}
__device__ __forceinline__ uint4 pk8(float4 a, float4 b) {
  uint4 o;
  o.x = (uint)f2bf(a.x) | ((uint)f2bf(a.y) << 16);
  o.y = (uint)f2bf(a.z) | ((uint)f2bf(a.w) << 16);
  o.z = (uint)f2bf(b.x) | ((uint)f2bf(b.y) << 16);
  o.w = (uint)f2bf(b.z) | ((uint)f2bf(b.w) << 16);
  return o;
}

// edge_index access: mode=1 -> int32 layout, mode=0 -> int64 (low words at even positions)
__device__ __forceinline__ int ld_src(const int* ei, int e, int mode) {
  return mode ? ei[e] : ei[2 * e];
}
__device__ __forceinline__ int ld_dst(const int* ei, int e, int mode) {
  return mode ? ei[Ee + e] : ei[2 * Ee + 2 * e];
}

__global__ void k_detect(const int* __restrict__ ei, int* __restrict__ flag) {
  if (blockIdx.x == 0 && threadIdx.x == 0) {
    int any = 0;
    for (int i = 0; i < 64; ++i) any |= ei[2 * i + 1];
    *flag = (any != 0) ? 1 : 0;
  }
}

__global__ void k_hist(const int* __restrict__ ei, const int* __restrict__ mode_p,
                       int* __restrict__ hist) {
  int e = blockIdx.x * 256 + threadIdx.x;
  int mode = *mode_p;
  atomicAdd(&hist[ld_dst(ei, e, mode)], 1);
}

__global__ void k_scan(const int* __restrict__ hist, int* __restrict__ cursor) {
  __shared__ int part[256];
  __shared__ int partx[256];
  int t = threadIdx.x;
  int base = t * (Nn / 256);
  int s = 0;
  for (int i = 0; i < Nn / 256; ++i) s += hist[base + i];
  part[t] = s;
  __syncthreads();
  if (t == 0) {
    int run = 0;
    for (int i = 0; i < 256; ++i) { partx[i] = run; run += part[i]; }
  }
  __syncthreads();
  int run = partx[t];
  for (int i = 0; i < Nn / 256; ++i) { int v = hist[base + i]; cursor[base + i] = run; run += v; }
}

__global__ void k_scatter(const int* __restrict__ ei, const int* __restrict__ mode_p,
                          int* __restrict__ cursor, int* __restrict__ perm,
                          int* __restrict__ dstS) {
  int e = blockIdx.x * 256 + threadIdx.x;
  int mode = *mode_p;
  int d = ld_dst(ei, e, mode);
  int pos = atomicAdd(&cursor[d], 1);
  perm[pos] = e;
  dstS[pos] = d;
}

__global__ void k_sq(const float* __restrict__ x, float* __restrict__ sq) {
  int n = blockIdx.x * 256 + threadIdx.x;
  const float4* p = (const float4*)(x + (size_t)n * Dd);
  float acc = 0.f;
#pragma unroll
  for (int i = 0; i < Dd / 4; ++i) {
    float4 v = p[i];
    acc += v.x * v.x + v.y * v.y + v.z * v.z + v.w * v.w;
  }
  sq[n] = acc;
}

// ---- weight repack: fp32 [K][N] -> bf16 MFMA-B layout, K' = 2K (hi rows then lo rows) ----
__global__ void k_repack(const float* __restrict__ sW1, const float* __restrict__ sW2,
                         const float* __restrict__ dW1, const float* __restrict__ dW2,
                         uint4* __restrict__ out) {
  int gid = blockIdx.x * 256 + threadIdx.x;
  const float* W; int K, N, u, obase;
  if (gid < 36864) {
    int i = gid / 12288; u = gid - i * 12288;
    W = sW1 + (size_t)i * 49152; K = 192; N = 256; obase = i * 12288;
  } else if (gid < 61440) {
    int g = gid - 36864; int i = g / 8192; u = g - i * 8192;
    W = sW2 + (size_t)i * 32768; K = 256; N = 128; obase = 36864 + i * 8192;
  } else if (gid < 94208) {
    int g = gid - 61440; int i = g / 16384; u = g - i * 16384;
    W = dW1 + (size_t)i * 65536; K = 256; N = 256; obase = 61440 + i * 16384;
  } else if (gid < 110592) {
    int g = gid - 94208; int i = g / 8192; u = g - i * 8192;
    W = dW2 + (size_t)i * 32768; K = 256; N = 128; obase = 94208 + i * 8192;
  } else return;
  int lane = u & 63;
  int t = u >> 6;
  int ksteps = K / 16;
  int kstep = t % ksteps, ntile = t / ksteps;
  int R = K / 32;
  bool lo = kstep >= R;
  int k0 = (lo ? kstep - R : kstep) * 32 + (lane >> 4) * 8;
  int n = ntile * 16 + (lane & 15);
  ushort v[8];
#pragma unroll
  for (int j = 0; j < 8; ++j) {
    float w = W[(size_t)(k0 + j) * N + n];
    ushort h = f2bf(w);
    v[j] = lo ? f2bf(w - bf2f(h)) : h;
  }
  uint4 o;
  o.x = (uint)v[0] | ((uint)v[1] << 16);
  o.y = (uint)v[2] | ((uint)v[3] << 16);
  o.z = (uint)v[4] | ((uint)v[5] << 16);
  o.w = (uint)v[6] | ((uint)v[7] << 16);
  out[obase + u] = o;
}

// ---- bf16x3 MFMA GEMM core for MLPs ----
template <int RK, int NT>
__device__ __forceinline__ void mfma3(const ushort* aB, int pitch, const uint4* __restrict__ Wp,
                                      int lane, floatx4 C[2][NT]) {
  int q = lane >> 4, m0 = lane & 15;
  short8 ahc[RK][2];
#pragma unroll
  for (int hm = 0; hm < 2; ++hm)
#pragma unroll
    for (int nt = 0; nt < NT; ++nt)
#pragma unroll
      for (int rr = 0; rr < 4; ++rr) C[hm][nt][rr] = 0.f;
#pragma unroll
  for (int s = 0; s < RK; ++s) {
    short8 ah0 = *(const short8*)(aB + m0 * pitch + s * 32 + q * 8);
    short8 ah1 = *(const short8*)(aB + (m0 + 16) * pitch + s * 32 + q * 8);
    short8 al0 = *(const short8*)(aB + m0 * pitch + (RK + s) * 32 + q * 8);
    short8 al1 = *(const short8*)(aB + (m0 + 16) * pitch + (RK + s) * 32 + q * 8);
    ahc[s][0] = ah0;
    ahc[s][1] = ah1;
#pragma unroll
    for (int nt = 0; nt < NT; ++nt) {
      uint4 bw = Wp[(nt * 2 * RK + s) * 64 + lane];
      short8 b = *(short8*)&bw;
      C[0][nt] = __builtin_amdgcn_mfma_f32_16x16x32_bf16(ah0, b, C[0][nt], 0, 0, 0);
      C[1][nt] = __builtin_amdgcn_mfma_f32_16x16x32_bf16(ah1, b, C[1][nt], 0, 0, 0);
      C[0][nt] = __builtin_amdgcn_mfma_f32_16x16x32_bf16(al0, b, C[0][nt], 0, 0, 0);
      C[1][nt] = __builtin_amdgcn_mfma_f32_16x16x32_bf16(al1, b, C[1][nt], 0, 0, 0);
    }
  }
#pragma unroll
  for (int s = 0; s < RK; ++s) {
#pragma unroll
    for (int nt = 0; nt < NT; ++nt) {
      uint4 bw = Wp[(nt * 2 * RK + RK + s) * 64 + lane];
      short8 b = *(short8*)&bw;
      C[0][nt] = __builtin_amdgcn_mfma_f32_16x16x32_bf16(ahc[s][0], b, C[0][nt], 0, 0, 0);
      C[1][nt] = __builtin_amdgcn_mfma_f32_16x16x32_bf16(ahc[s][1], b, C[1][nt], 0, 0, 0);
    }
  }
}

// ---- kNN prefilter: bf16 MFMA dots, writer-side distances, col-only survivor buffer ----
// __launch_bounds__(256,3): bound 4 forced 64-VGPR alloc -> scratch spill (round-5 regression).
// Natural alloc is ~84 VGPR (C[2][8]=64) -> 4 waves/SIMD fit anyway; LDS 39.4KB -> 4 blocks/CU.
__global__ __launch_bounds__(256, 3) void k_knn_part(const float* __restrict__ x,
                                                     const float* __restrict__ sq,
                                                     float* __restrict__ part_d,
                                                     int* __restrict__ part_i) {
  __shared__ __align__(16) ushort smXS[128 * PXS];  // bf16 src tile / fp32 dtile / merge bufs
  __shared__ float sqs_l[STILE];
  __shared__ ushort smBuf[BDEPTH * 256];  // survivor col buffer, [p][tid]
  float* dtile = (float*)smXS;            // [128][PDD], holds full distances d
  float* mbD = (float*)smXS;              // merge: 256*LDEPTH floats
  int* mbI = ((int*)smXS) + 2048;
  int tid = threadIdx.x;
  int wave = tid >> 6, lane = tid & 63;
  int quad = lane >> 4, n15 = lane & 15;
  int tileT = blockIdx.x >> 4;
  int split = blockIdx.x & 15;
  int tb = tileT * TT;
  int tg = tid >> 1, sl = tid & 1;

  // per-lane C-row target sq (8 output rows: mt in {0,1}, rr in 0..3)
  float sqi8[8];
#pragma unroll
  for (int mt = 0; mt < 2; ++mt)
#pragma unroll
    for (int rr = 0; rr < 4; ++rr)
      sqi8[mt * 4 + rr] = sq[tb + wave * 32 + mt * 16 + quad * 4 + rr];

  // A-fragments in registers (targets fixed for whole block)
  short8 afr[2][4];
#pragma unroll
  for (int mt = 0; mt < 2; ++mt) {
    int row = tb + wave * 32 + mt * 16 + n15;
#pragma unroll
    for (int ks = 0; ks < 4; ++ks) {
      int k0 = ks * 32 + quad * 8;
      float4 a = *(const float4*)&x[(size_t)row * Dd + k0];
      float4 b = *(const float4*)&x[(size_t)row * Dd + k0 + 4];
      uint4 p = pk8(a, b);
      afr[mt][ks] = *(short8*)&p;
    }
  }

  float bd[LDEPTH];
  int bi[LDEPTH];
#pragma unroll
  for (int p2 = 0; p2 < LDEPTH; ++p2) { bd[p2] = 3.0e38f; bi[p2] = 0x7fffffff; }
  int bcnt = 0;

  // exact depth-8 predicated sorted insert
  auto ins = [&](float d, int gidx) {
#pragma unroll
    for (int p = LDEPTH - 1; p >= 1; --p) {
      bool shift = d < bd[p - 1];
      bool here = (!shift) && (d < bd[p]);
      float nb = shift ? bd[p - 1] : (here ? d : bd[p]);
      int ni = shift ? bi[p - 1] : (here ? gidx : bi[p]);
      bd[p] = nb;
      bi[p] = ni;
    }
    if (d < bd[0]) { bd[0] = d; bi[0] = gidx; }
  };

#pragma unroll 1
  for (int st = 0; st < SWEEP / STILE; ++st) {
    int sb = split * SWEEP + st * STILE;
    __syncthreads();  // prior dtile/merge use of smXS done
    {
      int row = tid & 127, kh = (tid >> 7) * 64;
      int swz = ((row >> 3) & 7) << 3;
#pragma unroll
      for (int g = 0; g < 8; ++g) {
        int k0 = kh + g * 8;
        float4 a = *(const float4*)&x[(size_t)(sb + row) * Dd + k0];
        float4 b = *(const float4*)&x[(size_t)(sb + row) * Dd + k0 + 4];
        *(uint4*)&smXS[row * PXS + (k0 ^ swz)] = pk8(a, b);
      }
      if (tid < STILE) sqs_l[tid] = sq[sb + tid];
    }
    __syncthreads();
    floatx4 C[2][8];
#pragma unroll
    for (int mt = 0; mt < 2; ++mt)
#pragma unroll
      for (int nt = 0; nt < 8; ++nt)
#pragma unroll
        for (int rr = 0; rr < 4; ++rr) C[mt][nt][rr] = 0.f;
#pragma unroll
    for (int nt = 0; nt < 8; ++nt) {
      int s = nt * 16 + n15;
      int swz = ((s >> 3) & 7) << 3;
#pragma unroll
      for (int ks = 0; ks < 4; ++ks) {
        int k0 = ks * 32 + quad * 8;
        short8 bfr = *(const short8*)&smXS[s * PXS + (k0 ^ swz)];
        C[0][nt] = __builtin_amdgcn_mfma_f32_16x16x32_bf16(afr[0][ks], bfr, C[0][nt], 0, 0, 0);
        C[1][nt] = __builtin_amdgcn_mfma_f32_16x16x32_bf16(afr[1][ks], bfr, C[1][nt], 0, 0, 0);
      }
    }
    // source sq for this tile (both halves): col (nt*16+n15) in 0..127
    float sc[8];
#pragma unroll
    for (int nt = 0; nt < 8; ++nt) sc[nt] = sqs_l[nt * 16 + n15];
    __syncthreads();  // xs reads done -> alias as dtile
#pragma unroll
    for (int h = 0; h < 2; ++h) {
      if (h) __syncthreads();
      // writer computes full distance d = -2*dot + sq_i + sq_j
#pragma unroll
      for (int mt = 0; mt < 2; ++mt)
#pragma unroll
        for (int nt = 0; nt < 4; ++nt)
#pragma unroll
          for (int rr = 0; rr < 4; ++rr) {
            int row = wave * 32 + mt * 16 + quad * 4 + rr;
            int col = nt * 16 + n15;
            float d = fmaf(-2.f, C[mt][nt + 4 * h][rr], sqi8[mt * 4 + rr]) + sc[nt + 4 * h];
            dtile[row * PDD + col] = d;
          }
      __syncthreads();
      const float* drow = &dtile[tg * PDD];
#pragma unroll 1
      for (int j = 0; j < 32; ++j) {
        int col = sl + 2 * j;
        float d = drow[col];
        if (d < bd[LDEPTH - 1]) {
          if (bcnt < BDEPTH) {
            smBuf[bcnt * 256 + tid] = (ushort)col;
            ++bcnt;
          } else {
            ins(d, sb + h * 64 + col);  // overflow fallback (frequent only in early tiles)
          }
        }
      }
      // per-half flush while dtile is valid: re-read d by stored column
#pragma unroll 1
      for (int p = 0; p < BDEPTH; ++p) {
        bool act = p < bcnt;
        if (!__any(act)) break;
        if (act) {
          int col = smBuf[p * 256 + tid];
          float d = drow[col];
          ins(d, sb + h * 64 + col);
        }
      }
      bcnt = 0;
    }
  }

  // block-end: merge the two parity depth-8 lists per target -> sorted 16 per (target, split)
  __syncthreads();
#pragma unroll
  for (int o = 0; o < LDEPTH; ++o) {
    mbD[tid * LDEPTH + o] = bd[o];
    mbI[tid * LDEPTH + o] = bi[o];
  }
  __syncthreads();
  if (tid < TT) {
    const float* la = &mbD[(2 * tid) * LDEPTH];
    const float* lb = &mbD[(2 * tid + 1) * LDEPTH];
    const int* ia = &mbI[(2 * tid) * LDEPTH];
    const int* ib = &mbI[(2 * tid + 1) * LDEPTH];
    int pa = 0, pb = 0;
    size_t base = ((size_t)(tb + tid) * NSPLIT + split) * KK;
#pragma unroll
    for (int o = 0; o < KK; ++o) {
      float da = (pa < LDEPTH) ? la[pa] : 3.4e38f;
      float db = (pb < LDEPTH) ? lb[pb] : 3.4e38f;
      int iaa = (pa < LDEPTH) ? ia[pa] : 0x7fffffff;
      int ibb = (pb < LDEPTH) ? ib[pb] : 0x7fffffff;
      bool pick = (da < db) || (da == db && iaa < ibb);
      part_d[base + o] = pick ? da : db;
      part_i[base + o] = pick ? iaa : ibb;
      pa += pick ? 1 : 0;
      pb += pick ? 0 : 1;
    }
  }
}

// merge split lists -> approx top-32 candidate indices per target
__global__ void k_knn_merge(const float* __restrict__ part_d, const int* __restrict__ part_i,
                            int* __restrict__ cand) {
  int n = blockIdx.x * 256 + threadIdx.x;
  const float* pd = part_d + (size_t)n * NSPLIT * KK;
  const int* pi = part_i + (size_t)n * NSPLIT * KK;
  int pos[NSPLIT];
#pragma unroll
  for (int l = 0; l < NSPLIT; ++l) pos[l] = 0;
  for (int o = 0; o < MCAND; ++o) {
    float bestd = 3.3e38f;
    int besti = 0x7fffffff;
    int bestl = 0;
#pragma unroll
    for (int l = 0; l < NSPLIT; ++l) {
      if (pos[l] < KK) {
        float dd = pd[l * KK + pos[l]];
        int ii = pi[l * KK + pos[l]];
        if (dd < bestd || (dd == bestd && ii < besti)) { bestd = dd; besti = ii; bestl = l; }
      }
    }
    cand[(size_t)n * MCAND + o] = besti;
#pragma unroll
    for (int l = 0; l < NSPLIT; ++l) pos[l] += (l == bestl) ? 1 : 0;
  }
}

// exact fp32 rerank of 32 candidates -> ordered top-16 (same math/ties as full fp32 scan)
__global__ __launch_bounds__(256) void k_rerank(const float* __restrict__ x,
                                                const float* __restrict__ sq,
                                                const int* __restrict__ cand,
                                                int* __restrict__ knn_src) {
  int tid = threadIdx.x;
  int wave = tid >> 6, lane = tid & 63;
  int t = blockIdx.x * 4 + wave;
  int c = lane & 31, h = lane >> 5;
  int idx = cand[(size_t)t * MCAND + c];
  const float* xt = x + (size_t)t * Dd + h * 64;
  const float* xc = x + (size_t)idx * Dd + h * 64;
  float s = 0.f;
#pragma unroll
  for (int g = 0; g < 16; ++g) {
    float4 a = *(const float4*)&xt[g * 4];
    float4 b = *(const float4*)&xc[g * 4];
    s += a.x * b.x + a.y * b.y + a.z * b.z + a.w * b.w;
  }
  s += __shfl_xor(s, 32);
  float d = fmaf(-2.f, s, sq[t]) + sq[idx];
  int rank = 0;
#pragma unroll
  for (int j = 0; j < 32; ++j) {
    float dj = __shfl(d, j);
    int ij = __shfl(idx, j);
    rank += ((dj < d) || (dj == d && ij < idx)) ? 1 : 0;
  }
  if (lane < 32 && rank < KK) knn_src[t * KK + rank] = idx;
}

// ---------------- static message MLP (bf16x3 MFMA) + grouped scatter-add ----------------
__global__ __launch_bounds__(256, 3) void k_static_msg(
    const float* __restrict__ xs, const float* __restrict__ ea, const int* __restrict__ ei,
    const int* __restrict__ mode_p, const int* __restrict__ perm, const int* __restrict__ dstS,
    const uint4* __restrict__ W1p, const float* __restrict__ b1,
    const uint4* __restrict__ W2p, const float* __restrict__ b2, float* __restrict__ agg) {
  __shared__ __align__(16) ushort smH[32 * 520];
  __shared__ int dstLoc[32];
  int tid = threadIdx.x;
  int wave = tid >> 6, lane = tid & 63;
  int pb = blockIdx.x * 32;
  int mode = *mode_p;
  int r = tid & 31, q8 = tid >> 5;
  int p = pb + r;
  int e = perm[p];
  int ds = dstS[p];
  int sr = ld_src(ei, e, mode);
  if (q8 == 0) dstLoc[r] = ds;
  const float* eap = ea + (size_t)e * DEe;
  const float* xsp = xs + (size_t)sr * Dd;
  const float* xdp = xs + (size_t)ds * Dd;
#pragma unroll
  for (int it = 0; it < 6; ++it) {
    int f = q8 * 24 + it * 4;
    float4 v;
    if (f < 64) {
      v = *(const float4*)&eap[f];
    } else {
      float4 a = *(const float4*)&xsp[f - 64];
      float4 b = *(const float4*)&xdp[f - 64];
      v = make_float4(a.x - b.x, a.y - b.y, a.z - b.z, a.w - b.w);
    }
    uint2 hi, lo;
    cvt_hilo(v, &hi, &lo);
    *(uint2*)&smH[r * 392 + f] = hi;
    *(uint2*)&smH[r * 392 + 192 + f] = lo;
  }
  __syncthreads();
  floatx4 C1[2][4];
  mfma3<6, 4>(smH, 392, W1p + (size_t)wave * 4 * 12 * 64, lane, C1);
  __syncthreads();
  {
    int q = lane >> 4, n15 = lane & 15;
#pragma unroll
    for (int hm = 0; hm < 2; ++hm)
#pragma unroll
      for (int nt = 0; nt < 4; ++nt) {
        int n = wave * 64 + nt * 16 + n15;
        float bv = b1[n];
#pragma unroll
        for (int rr = 0; rr < 4; ++rr) {
          int m = hm * 16 + q * 4 + rr;
          float h = fmaxf(C1[hm][nt][rr] + bv, 0.f);
          ushort hh = f2bf(h);
          smH[m * 520 + n] = hh;
          smH[m * 520 + 256 + n] = f2bf(h - bf2f(hh));
        }
      }
  }
  __syncthreads();
  floatx4 C2[2][2];
  mfma3<8, 2>(smH, 520, W2p + (size_t)wave * 2 * 16 * 64, lane, C2);
  __syncthreads();
  float* smM = (float*)smH;
  {
    int q = lane >> 4, n15 = lane & 15;
#pragma unroll
    for (int hm = 0; hm < 2; ++hm)
#pragma unroll
      for (int nt = 0; nt < 2; ++nt) {
        int n = wave * 32 + nt * 16 + n15;
        float bv = b2[n];
#pragma unroll
        for (int rr = 0; rr < 4; ++rr) {
          int m = hm * 16 + q * 4 + rr;
          smM[m * 132 + n] = fmaxf(C2[hm][nt][rr] + bv, 0.f);
        }
      }
  }
  __syncthreads();
  int col = tid & 127, half = tid >> 7;
  int r0 = half * 16;
  float run = smM[r0 * 132 + col];
  int prevd = dstLoc[r0];
  for (int rr = 1; rr < 16; ++rr) {
    int row = r0 + rr;
    int dd2 = dstLoc[row];
    float v = smM[row * 132 + col];
    if (dd2 != prevd) {
      atomicAdd(&agg[(size_t)prevd * Dd + col], run);
      run = v;
      prevd = dd2;
    } else {
      run += v;
    }
  }
  atomicAdd(&agg[(size_t)prevd * Dd + col], run);
}

// ---------------- dynamic (kNN) message MLP (bf16x3 MFMA), atomic-free ----------------
__global__ __launch_bounds__(256, 3) void k_dyn_msg(
    const float* __restrict__ xd, const int* __restrict__ knn, const uint4* __restrict__ W1p,
    const float* __restrict__ b1, const uint4* __restrict__ W2p, const float* __restrict__ b2,
    float* __restrict__ agg) {
  __shared__ __align__(16) ushort smH[32 * 520];
  int tid = threadIdx.x;
  int wave = tid >> 6, lane = tid & 63;
  int nb2 = blockIdx.x * 2;
  int r = tid & 31, q8 = tid >> 5;
  int tgt = nb2 + (r >> 4);
  int nj = knn[tgt * KK + (r & 15)];
  const float* xip = xd + (size_t)tgt * Dd;
  const float* xjp = xd + (size_t)nj * Dd;
#pragma unroll
  for (int it = 0; it < 8; ++it) {
    int f = q8 * 32 + it * 4;
    float4 v;
    if (f < 128) {
      v = *(const float4*)&xip[f];
    } else {
      float4 a = *(const float4*)&xjp[f - 128];
      float4 b = *(const float4*)&xip[f - 128];
      v = make_float4(a.x - b.x, a.y - b.y, a.z - b.z, a.w - b.w);
    }
    uint2 hi, lo;
    cvt_hilo(v, &hi, &lo);
    *(uint2*)&smH[r * 520 + f] = hi;
    *(uint2*)&smH[r * 520 + 256 + f] = lo;
  }
  __syncthreads();
  floatx4 C1[2][4];
  mfma3<8, 4>(smH, 520, W1p + (size_t)wave * 4 * 16 * 64, lane, C1);
  __syncthreads();
  {
    int q = lane >> 4, n15 = lane & 15;
#pragma unroll
    for (int hm = 0; hm < 2; ++hm)
#pragma unroll
      for (int nt = 0; nt < 4; ++nt) {
        int n = wave * 64 + nt * 16 + n15;
        float bv = b1[n];
#pragma unroll
        for (int rr = 0; rr < 4; ++rr) {
          int m = hm * 16 + q * 4 + rr;
          float h = fmaxf(C1[hm][nt][rr] + bv, 0.f);
          ushort hh = f2bf(h);
          smH[m * 520 + n] = hh;
          smH[m * 520 + 256 + n] = f2bf(h - bf2f(hh));
        }
      }
  }
  __syncthreads();
  floatx4 C2[2][2];
  mfma3<8, 2>(smH, 520, W2p + (size_t)wave * 2 * 16 * 64, lane, C2);
  int q = lane >> 4, n15 = lane & 15;
#pragma unroll
  for (int hm = 0; hm < 2; ++hm)
#pragma unroll
    for (int nt = 0; nt < 2; ++nt) {
      int n = wave * 32 + nt * 16 + n15;
      float bv = b2[n];
      float s = 0.f;
#pragma unroll
      for (int rr = 0; rr < 4; ++rr) s += fmaxf(C2[hm][nt][rr] + bv, 0.f);
      s += __shfl_xor(s, 16);
      s += __shfl_xor(s, 32);
      if (q == 0) agg[(size_t)(nb2 + hm) * Dd + n] = s;
    }
}

// ---------------- fp32 fused 2-layer MLP core (node update / fuse) ----------------
__device__ __forceinline__ void mlp_l1(int tid, int indim, const float* __restrict__ W1,
                                       const float* __restrict__ b1, float* smA, float* smB) {
  int rg = tid >> 5, cg = tid & 31;
  float acc[32];
#pragma unroll
  for (int i = 0; i < 32; ++i) acc[i] = 0.f;
  for (int kc = 0; kc < indim / 8; ++kc) {
    const float* W1g = W1 + (size_t)kc * 8 * Hh;
    *(float4*)&smB[tid * 4] = *(const float4*)&W1g[tid * 4];
    *(float4*)&smB[1024 + tid * 4] = *(const float4*)&W1g[1024 + tid * 4];
    __syncthreads();
#pragma unroll
    for (int k = 0; k < 8; ++k) {
      int kk = kc * 8 + k;
      float4 a0 = *(const float4*)&smA[kk * 32 + rg * 4];
      float4 b0 = *(const float4*)&smB[k * Hh + cg * 8];
      float4 b1v = *(const float4*)&smB[k * Hh + cg * 8 + 4];
      float av[4] = {a0.x, a0.y, a0.z, a0.w};
      float bv[8] = {b0.x, b0.y, b0.z, b0.w, b1v.x, b1v.y, b1v.z, b1v.w};
#pragma unroll
      for (int rr = 0; rr < 4; ++rr)
#pragma unroll
        for (int cc = 0; cc < 8; ++cc) acc[rr * 8 + cc] += av[rr] * bv[cc];
    }
    __syncthreads();
  }
  float4 bb0 = *(const float4*)&b1[cg * 8];
  float4 bb1 = *(const float4*)&b1[cg * 8 + 4];
  float bs[8] = {bb0.x, bb0.y, bb0.z, bb0.w, bb1.x, bb1.y, bb1.z, bb1.w};
#pragma unroll
  for (int rr = 0; rr < 4; ++rr) {
    int row = rg * 4 + rr;
    float4 h0, h1;
    h0.x = fmaxf(acc[rr * 8 + 0] + bs[0], 0.f);
    h0.y = fmaxf(acc[rr * 8 + 1] + bs[1], 0.f);
    h0.z = fmaxf(acc[rr * 8 + 2] + bs[2], 0.f);
    h0.w = fmaxf(acc[rr * 8 + 3] + bs[3], 0.f);
    h1.x = fmaxf(acc[rr * 8 + 4] + bs[4], 0.f);
    h1.y = fmaxf(acc[rr * 8 + 5] + bs[5], 0.f);
    h1.z = fmaxf(acc[rr * 8 + 6] + bs[6], 0.f);
    h1.w = fmaxf(acc[rr * 8 + 7] + bs[7], 0.f);
    *(float4*)&smA[row * 260 + cg * 8] = h0;
    *(float4*)&smA[row * 260 + cg * 8 + 4] = h1;
  }
  __syncthreads();
}

__device__ __forceinline__ void mlp_l2(int tid, const float* __restrict__ W2,
                                       const float* smA, float* smB, float acc2[16]) {
  int rg2 = tid >> 5, cg2 = tid & 31;
#pragma unroll
  for (int i = 0; i < 16; ++i) acc2[i] = 0.f;
  for (int kc = 0; kc < Hh / 16; ++kc) {
    const float* W2g = W2 + (size_t)kc * 16 * Dd;
    *(float4*)&smB[tid * 4] = *(const float4*)&W2g[tid * 4];
    *(float4*)&smB[1024 + tid * 4] = *(const float4*)&W2g[1024 + tid * 4];
    __syncthreads();
#pragma unroll
    for (int k = 0; k < 16; ++k) {
      int kk = kc * 16 + k;
      float4 b0 = *(const float4*)&smB[k * Dd + cg2 * 4];
#pragma unroll
      for (int rr = 0; rr < 4; ++rr) {
        float a = smA[(rg2 * 4 + rr) * 260 + kk];
        acc2[rr * 4 + 0] += a * b0.x;
        acc2[rr * 4 + 1] += a * b0.y;
        acc2[rr * 4 + 2] += a * b0.z;
        acc2[rr * 4 + 3] += a * b0.w;
      }
    }
    __syncthreads();
  }
}

__global__ __launch_bounds__(256, 3) void k_node_mlp2(
    const float* __restrict__ in1, const float* __restrict__ in2, int indim,
    const float* __restrict__ W1, const float* __restrict__ b1, const float* __restrict__ W2,
    const float* __restrict__ b2, float* __restrict__ out) {
  __shared__ float smA[32 * 260];
  __shared__ float smB[2048];
  int tid = threadIdx.x;
  int nb = blockIdx.x * 32;
  int r = tid & 31, q = tid >> 5;
  for (int pass = 0; pass < indim / 32; ++pass) {
    int k0 = pass * 32 + q * 4;
    float4 v;
    if (k0 < Dd)
      v = *(const float4*)&in1[(size_t)(nb + r) * Dd + k0];
    else
      v = *(const float4*)&in2[(size_t)(nb + r) * Dd + (k0 - Dd)];
    smA[(k0 + 0) * 32 + r] = v.x;
    smA[(k0 + 1) * 32 + r] = v.y;
    smA[(k0 + 2) * 32 + r] = v.z;
    smA[(k0 + 3) * 32 + r] = v.w;
  }
  __syncthreads();
  mlp_l1(tid, indim, W1, b1, smA, smB);
  float acc2[16];
  mlp_l2(tid, W2, smA, smB, acc2);
  int rg2 = tid >> 5, cg2 = tid & 31;
  float4 ob = *(const float4*)&b2[cg2 * 4];
#pragma unroll
  for (int rr = 0; rr < 4; ++rr) {
    float4 o;
    o.x = fmaxf(acc2[rr * 4 + 0] + ob.x, 0.f);
    o.y = fmaxf(acc2[rr * 4 + 1] + ob.y, 0.f);
    o.z = fmaxf(acc2[rr * 4 + 2] + ob.z, 0.f);
    o.w = fmaxf(acc2[rr * 4 + 3] + ob.w, 0.f);
    *(float4*)&out[(size_t)(nb + rg2 * 4 + rr) * Dd + cg2 * 4] = o;
  }
}

__global__ __launch_bounds__(256) void k_refine(const float* __restrict__ ein,
                                                const float* __restrict__ rW,
                                                const float* __restrict__ rb,
                                                float* __restrict__ eout) {
  __shared__ float lea[16 * 64];
  __shared__ float ldsW[64 * 64];
  int tid = threadIdx.x;
  int eb = blockIdx.x * 16;
  *(float4*)&lea[tid * 4] = *(const float4*)&ein[(size_t)eb * DEe + tid * 4];
#pragma unroll
  for (int m = 0; m < 4; ++m) {
    int i4 = tid + m * 256;
    *(float4*)&ldsW[i4 * 4] = *(const float4*)&rW[i4 * 4];
  }
  __syncthreads();
  int j = tid & 63, eg = tid >> 6;
  float bias = rb[j];
  float acc0 = 0.f, acc1 = 0.f, acc2 = 0.f, acc3 = 0.f;
#pragma unroll 8
  for (int k = 0; k < 64; ++k) {
    float w = ldsW[k * 64 + j];
    acc0 += lea[(eg + 0) * 64 + k] * w;
    acc1 += lea[(eg + 4) * 64 + k] * w;
    acc2 += lea[(eg + 8) * 64 + k] * w;
    acc3 += lea[(eg + 12) * 64 + k] * w;
  }
  eout[(size_t)(eb + eg + 0) * DEe + j] = fmaxf(acc0 + bias, 0.f);
  eout[(size_t)(eb + eg + 4) * DEe + j] = fmaxf(acc1 + bias, 0.f);
  eout[(size_t)(eb + eg + 8) * DEe + j] = fmaxf(acc2 + bias, 0.f);
  eout[(size_t)(eb + eg + 12) * DEe + j] = fmaxf(acc3 + bias, 0.f);
}

extern "C" void kernel_launch(void* const* d_in, const int* in_sizes, int n_in, void* d_out,
                              int out_size, void* d_ws, size_t ws_size, hipStream_t stream) {
  (void)in_sizes; (void)n_in; (void)out_size; (void)ws_size;
  const float* x = (const float*)d_in[0];
  const float* edge_attr = (const float*)d_in[1];
  const float* sW1 = (const float*)d_in[2];
  const float* sb1 = (const float*)d_in[3];
  const float* sW2 = (const float*)d_in[4];
  const float* sb2 = (const float*)d_in[5];
  const float* uW1 = (const float*)d_in[6];
  const float* ub1 = (const float*)d_in[7];
  const float* uW2 = (const float*)d_in[8];
  const float* ub2 = (const float*)d_in[9];
  const float* rW = (const float*)d_in[10];
  const float* rb = (const float*)d_in[11];
  const float* dW1 = (const float*)d_in[12];
  const float* db1 = (const float*)d_in[13];
  const float* dW2 = (const float*)d_in[14];
  const float* db2 = (const float*)d_in[15];
  const float* dUW1 = (const float*)d_in[16];
  const float* dUb1 = (const float*)d_in[17];
  const float* dUW2 = (const float*)d_in[18];
  const float* dUb2 = (const float*)d_in[19];
  const float* fW1 = (const float*)d_in[20];
  const float* fb1 = (const float*)d_in[21];
  const float* fW2 = (const float*)d_in[22];
  const float* fb2 = (const float*)d_in[23];
  const int* ei = (const int*)d_in[24];
  float* out = (float*)d_out;

  float* wsf = (float*)d_ws;
  size_t off = 0;
  float* ea_ws = wsf + off; off += (size_t)Ee * DEe;
  float* xs_ws = wsf + off; off += (size_t)Nn * Dd;
  float* xd_ws = wsf + off; off += (size_t)Nn * Dd;
  float* agg = wsf + off;   off += (size_t)Nn * Dd;
  float* sq = wsf + off;    off += Nn;
  int* knn_src = (int*)(wsf + off); off += (size_t)Nn * KK;
  int* hist = (int*)(wsf + off);   off += Nn;
  int* cursor = (int*)(wsf + off); off += Nn;
  int* perm = (int*)(wsf + off);   off += Ee;
  int* dstS = (int*)(wsf + off);   off += Ee;
  int* modep = (int*)(wsf + off);  off += 1;
  off = (off + 3) & ~(size_t)3;  // 16B align for uint4
  uint4* wpk = (uint4*)(wsf + off); off += (size_t)110592 * 4;
  // kNN scratch overlaps ea_ws (edge_attr refinement dead before dynamic branch)
  float* part_d = ea_ws;
  int* part_i = (int*)(ea_ws + (size_t)Nn * NSPLIT * KK);
  int* cand = (int*)(ea_ws + 2 * (size_t)Nn * NSPLIT * KK);

  // edge_index probe + counting sort by dst
  k_detect<<<1, 64, 0, stream>>>(ei, modep);
  hipMemsetAsync(hist, 0, Nn * sizeof(int), stream);
  k_hist<<<Ee / 256, 256, 0, stream>>>(ei, modep, hist);
  k_scan<<<1, 256, 0, stream>>>(hist, cursor);
  k_scatter<<<Ee / 256, 256, 0, stream>>>(ei, modep, cursor, perm, dstS);

  // repack all msg-MLP weights into bf16 hi/lo MFMA-B layout
  k_repack<<<432, 256, 0, stream>>>(sW1, sW2, dW1, dW2, wpk);

  // ---- static branch: 3 convs + 2 refiners ----
  const float* xs_cur = x;
  const float* ea_cur = edge_attr;
  for (int i = 0; i < 3; ++i) {
    hipMemsetAsync(agg, 0, (size_t)Nn * Dd * sizeof(float), stream);
    k_static_msg<<<Ee / 32, 256, 0, stream>>>(
        xs_cur, ea_cur, ei, modep, perm, dstS, wpk + (size_t)i * 12288,
        sb1 + (size_t)i * Hh, wpk + 36864 + (size_t)i * 8192, sb2 + (size_t)i * Dd, agg);
    k_node_mlp2<<<Nn / 32, 256, 0, stream>>>(
        agg, (const float*)nullptr, Dd, uW1 + (size_t)i * Dd * Hh, ub1 + (size_t)i * Hh,
        uW2 + (size_t)i * Hh * Dd, ub2 + (size_t)i * Dd, xs_ws);
    xs_cur = xs_ws;
    if (i < 2) {
      k_refine<<<Ee / 16, 256, 0, stream>>>(ea_cur, rW + (size_t)i * DEe * DEe,
                                            rb + (size_t)i * DEe, ea_ws);
      ea_cur = ea_ws;
    }
  }

  // ---- dynamic branch: 2 kNN convs (MFMA prefilter -> merge32 -> exact rerank) ----
  const float* xd_cur = x;
  for (int i = 0; i < 2; ++i) {
    k_sq<<<Nn / 256, 256, 0, stream>>>(xd_cur, sq);
    k_knn_part<<<(Nn / TT) * NSPLIT, 256, 0, stream>>>(xd_cur, sq, part_d, part_i);
    k_knn_merge<<<Nn / 256, 256, 0, stream>>>(part_d, part_i, cand);
    k_rerank<<<Nn / 4, 256, 0, stream>>>(xd_cur, sq, cand, knn_src);
    k_dyn_msg<<<Nn / 2, 256, 0, stream>>>(
        xd_cur, knn_src, wpk + 61440 + (size_t)i * 16384, db1 + (size_t)i * Hh,
        wpk + 94208 + (size_t)i * 8192, db2 + (size_t)i * Dd, agg);
    k_node_mlp2<<<Nn / 32, 256, 0, stream>>>(
        agg, (const float*)nullptr, Dd, dUW1 + (size_t)i * Dd * Hh, dUb1 + (size_t)i * Hh,
        dUW2 + (size_t)i * Hh * Dd, dUb2 + (size_t)i * Dd, xd_ws);
    xd_cur = xd_ws;
  }

  // ---- fuse MLP ----
  k_node_mlp2<<<Nn / 32, 256, 0, stream>>>(xs_ws, xd_ws, 2 * Dd, fW1, fb1, fW2, fb2, out);
}

// Round 7
// 2907.344 us; speedup vs baseline: 1.0996x; 1.0241x over previous
//
#include <hip/hip_runtime.h>

#define Nn 16384
#define Ee 262144
#define Dd 128
#define DEe 64
#define Hh 256
#define KK 16
#define NSPLIT 16
#define TT 128      /* knn targets per block */
#define STILE 128   /* knn source tile */
#define SWEEP (Nn / NSPLIT)
#define PXS 136     /* bf16 source-tile pitch (ushorts) */
#define PDD 68      /* dtile pitch (floats); 68*4=272B = 16B-aligned rows for b128 scan */
#define MCAND 32    /* rerank candidates per target */
#define BDEPTH 8    /* per-lane survivor buffer depth */
#define LDEPTH 8    /* per-parity-thread top list depth (2x8 -> merged 16/split) */

typedef __attribute__((ext_vector_type(8))) short short8;
typedef __attribute__((ext_vector_type(4))) float floatx4;

// ---------- bf16 helpers ----------
__device__ __forceinline__ ushort f2bf(float f) {
  uint u = __float_as_uint(f);
  u += 0x7fffu + ((u >> 16) & 1u);
  return (ushort)(u >> 16);
}
__device__ __forceinline__ float bf2f(ushort h) { return __uint_as_float(((uint)h) << 16); }
__device__ __forceinline__ void cvt_hilo(float4 v, uint2* hi, uint2* lo) {
  ushort h0 = f2bf(v.x), h1 = f2bf(v.y), h2 = f2bf(v.z), h3 = f2bf(v.w);
  ushort l0 = f2bf(v.x - bf2f(h0)), l1 = f2bf(v.y - bf2f(h1));
  ushort l2 = f2bf(v.z - bf2f(h2)), l3 = f2bf(v.w - bf2f(h3));
  hi->x = (uint)h0 | ((uint)h1 << 16); hi->y = (uint)h2 | ((uint)h3 << 16);
  lo->x = (uint)l0 | ((uint)l1 << 16); lo->y = (uint)l2 | ((uint)l3 << 16);
}
__device__ __forceinline__ uint4 pk8(float4 a, float4 b) {
  uint4 o;
  o.x = (uint)f2bf(a.x) | ((uint)f2bf(a.y) << 16);
  o.y = (uint)f2bf(a.z) | ((uint)f2bf(a.w) << 16);
  o.z = (uint)f2bf(b.x) | ((uint)f2bf(b.y) << 16);
  o.w = (uint)f2bf(b.z) | ((uint)f2bf(b.w) << 16);
  return o;
}

// edge_index access: mode=1 -> int32 layout, mode=0 -> int64 (low words at even positions)
__device__ __forceinline__ int ld_src(const int* ei, int e, int mode) {
  return mode ? ei[e] : ei[2 * e];
}
__device__ __forceinline__ int ld_dst(const int* ei, int e, int mode) {
  return mode ? ei[Ee + e] : ei[2 * Ee + 2 * e];
}

__global__ void k_detect(const int* __restrict__ ei, int* __restrict__ flag) {
  if (blockIdx.x == 0 && threadIdx.x == 0) {
    int any = 0;
    for (int i = 0; i < 64; ++i) any |= ei[2 * i + 1];
    *flag = (any != 0) ? 1 : 0;
  }
}

__global__ void k_hist(const int* __restrict__ ei, const int* __restrict__ mode_p,
                       int* __restrict__ hist) {
  int e = blockIdx.x * 256 + threadIdx.x;
  int mode = *mode_p;
  atomicAdd(&hist[ld_dst(ei, e, mode)], 1);
}

__global__ void k_scan(const int* __restrict__ hist, int* __restrict__ cursor) {
  __shared__ int part[256];
  __shared__ int partx[256];
  int t = threadIdx.x;
  int base = t * (Nn / 256);
  int s = 0;
  for (int i = 0; i < Nn / 256; ++i) s += hist[base + i];
  part[t] = s;
  __syncthreads();
  if (t == 0) {
    int run = 0;
    for (int i = 0; i < 256; ++i) { partx[i] = run; run += part[i]; }
  }
  __syncthreads();
  int run = partx[t];
  for (int i = 0; i < Nn / 256; ++i) { int v = hist[base + i]; cursor[base + i] = run; run += v; }
}

__global__ void k_scatter(const int* __restrict__ ei, const int* __restrict__ mode_p,
                          int* __restrict__ cursor, int* __restrict__ perm,
                          int* __restrict__ dstS) {
  int e = blockIdx.x * 256 + threadIdx.x;
  int mode = *mode_p;
  int d = ld_dst(ei, e, mode);
  int pos = atomicAdd(&cursor[d], 1);
  perm[pos] = e;
  dstS[pos] = d;
}

__global__ void k_sq(const float* __restrict__ x, float* __restrict__ sq) {
  int n = blockIdx.x * 256 + threadIdx.x;
  const float4* p = (const float4*)(x + (size_t)n * Dd);
  float acc = 0.f;
#pragma unroll
  for (int i = 0; i < Dd / 4; ++i) {
    float4 v = p[i];
    acc += v.x * v.x + v.y * v.y + v.z * v.z + v.w * v.w;
  }
  sq[n] = acc;
}

// ---- weight repack: fp32 [K][N] -> bf16 MFMA-B layout, K' = 2K (hi rows then lo rows) ----
__global__ void k_repack(const float* __restrict__ sW1, const float* __restrict__ sW2,
                         const float* __restrict__ dW1, const float* __restrict__ dW2,
                         uint4* __restrict__ out) {
  int gid = blockIdx.x * 256 + threadIdx.x;
  const float* W; int K, N, u, obase;
  if (gid < 36864) {
    int i = gid / 12288; u = gid - i * 12288;
    W = sW1 + (size_t)i * 49152; K = 192; N = 256; obase = i * 12288;
  } else if (gid < 61440) {
    int g = gid - 36864; int i = g / 8192; u = g - i * 8192;
    W = sW2 + (size_t)i * 32768; K = 256; N = 128; obase = 36864 + i * 8192;
  } else if (gid < 94208) {
    int g = gid - 61440; int i = g / 16384; u = g - i * 16384;
    W = dW1 + (size_t)i * 65536; K = 256; N = 256; obase = 61440 + i * 16384;
  } else if (gid < 110592) {
    int g = gid - 94208; int i = g / 8192; u = g - i * 8192;
    W = dW2 + (size_t)i * 32768; K = 256; N = 128; obase = 94208 + i * 8192;
  } else return;
  int lane = u & 63;
  int t = u >> 6;
  int ksteps = K / 16;
  int kstep = t % ksteps, ntile = t / ksteps;
  int R = K / 32;
  bool lo = kstep >= R;
  int k0 = (lo ? kstep - R : kstep) * 32 + (lane >> 4) * 8;
  int n = ntile * 16 + (lane & 15);
  ushort v[8];
#pragma unroll
  for (int j = 0; j < 8; ++j) {
    float w = W[(size_t)(k0 + j) * N + n];
    ushort h = f2bf(w);
    v[j] = lo ? f2bf(w - bf2f(h)) : h;
  }
  uint4 o;
  o.x = (uint)v[0] | ((uint)v[1] << 16);
  o.y = (uint)v[2] | ((uint)v[3] << 16);
  o.z = (uint)v[4] | ((uint)v[5] << 16);
  o.w = (uint)v[6] | ((uint)v[7] << 16);
  out[obase + u] = o;
}

// ---- bf16x3 MFMA GEMM core for MLPs ----
template <int RK, int NT>
__device__ __forceinline__ void mfma3(const ushort* aB, int pitch, const uint4* __restrict__ Wp,
                                      int lane, floatx4 C[2][NT]) {
  int q = lane >> 4, m0 = lane & 15;
  short8 ahc[RK][2];
#pragma unroll
  for (int hm = 0; hm < 2; ++hm)
#pragma unroll
    for (int nt = 0; nt < NT; ++nt)
#pragma unroll
      for (int rr = 0; rr < 4; ++rr) C[hm][nt][rr] = 0.f;
#pragma unroll
  for (int s = 0; s < RK; ++s) {
    short8 ah0 = *(const short8*)(aB + m0 * pitch + s * 32 + q * 8);
    short8 ah1 = *(const short8*)(aB + (m0 + 16) * pitch + s * 32 + q * 8);
    short8 al0 = *(const short8*)(aB + m0 * pitch + (RK + s) * 32 + q * 8);
    short8 al1 = *(const short8*)(aB + (m0 + 16) * pitch + (RK + s) * 32 + q * 8);
    ahc[s][0] = ah0;
    ahc[s][1] = ah1;
#pragma unroll
    for (int nt = 0; nt < NT; ++nt) {
      uint4 bw = Wp[(nt * 2 * RK + s) * 64 + lane];
      short8 b = *(short8*)&bw;
      C[0][nt] = __builtin_amdgcn_mfma_f32_16x16x32_bf16(ah0, b, C[0][nt], 0, 0, 0);
      C[1][nt] = __builtin_amdgcn_mfma_f32_16x16x32_bf16(ah1, b, C[1][nt], 0, 0, 0);
      C[0][nt] = __builtin_amdgcn_mfma_f32_16x16x32_bf16(al0, b, C[0][nt], 0, 0, 0);
      C[1][nt] = __builtin_amdgcn_mfma_f32_16x16x32_bf16(al1, b, C[1][nt], 0, 0, 0);
    }
  }
#pragma unroll
  for (int s = 0; s < RK; ++s) {
#pragma unroll
    for (int nt = 0; nt < NT; ++nt) {
      uint4 bw = Wp[(nt * 2 * RK + RK + s) * 64 + lane];
      short8 b = *(short8*)&bw;
      C[0][nt] = __builtin_amdgcn_mfma_f32_16x16x32_bf16(ahc[s][0], b, C[0][nt], 0, 0, 0);
      C[1][nt] = __builtin_amdgcn_mfma_f32_16x16x32_bf16(ahc[s][1], b, C[1][nt], 0, 0, 0);
    }
  }
}

// ---- kNN prefilter: bf16 MFMA dots, writer-side distances, float4 contiguous scan ----
__global__ __launch_bounds__(256, 3) void k_knn_part(const float* __restrict__ x,
                                                     const float* __restrict__ sq,
                                                     float* __restrict__ part_d,
                                                     int* __restrict__ part_i) {
  __shared__ __align__(16) ushort smXS[128 * PXS];  // bf16 src tile / fp32 dtile / merge bufs
  __shared__ float sqs_l[STILE];
  __shared__ ushort smBuf[BDEPTH * 256];  // survivor col buffer, [p][tid]
  float* dtile = (float*)smXS;            // [128][PDD], holds full distances d
  float* mbD = (float*)smXS;              // merge: 256*LDEPTH floats
  int* mbI = ((int*)smXS) + 2048;
  int tid = threadIdx.x;
  int wave = tid >> 6, lane = tid & 63;
  int quad = lane >> 4, n15 = lane & 15;
  int tileT = blockIdx.x >> 4;
  int split = blockIdx.x & 15;
  int tb = tileT * TT;
  int tg = tid >> 1, sl = tid & 1;

  // per-lane C-row target sq (8 output rows: mt in {0,1}, rr in 0..3)
  float sqi8[8];
#pragma unroll
  for (int mt = 0; mt < 2; ++mt)
#pragma unroll
    for (int rr = 0; rr < 4; ++rr)
      sqi8[mt * 4 + rr] = sq[tb + wave * 32 + mt * 16 + quad * 4 + rr];

  // A-fragments in registers (targets fixed for whole block)
  short8 afr[2][4];
#pragma unroll
  for (int mt = 0; mt < 2; ++mt) {
    int row = tb + wave * 32 + mt * 16 + n15;
#pragma unroll
    for (int ks = 0; ks < 4; ++ks) {
      int k0 = ks * 32 + quad * 8;
      float4 a = *(const float4*)&x[(size_t)row * Dd + k0];
      float4 b = *(const float4*)&x[(size_t)row * Dd + k0 + 4];
      uint4 p = pk8(a, b);
      afr[mt][ks] = *(short8*)&p;
    }
  }

  float bd[LDEPTH];
  int bi[LDEPTH];
#pragma unroll
  for (int p2 = 0; p2 < LDEPTH; ++p2) { bd[p2] = 3.0e38f; bi[p2] = 0x7fffffff; }
  int bcnt = 0;

  // exact depth-8 predicated sorted insert
  auto ins = [&](float d, int gidx) {
#pragma unroll
    for (int p = LDEPTH - 1; p >= 1; --p) {
      bool shift = d < bd[p - 1];
      bool here = (!shift) && (d < bd[p]);
      float nb = shift ? bd[p - 1] : (here ? d : bd[p]);
      int ni = shift ? bi[p - 1] : (here ? gidx : bi[p]);
      bd[p] = nb;
      bi[p] = ni;
    }
    if (d < bd[0]) { bd[0] = d; bi[0] = gidx; }
  };

#pragma unroll 1
  for (int st = 0; st < SWEEP / STILE; ++st) {
    int sb = split * SWEEP + st * STILE;
    __syncthreads();  // prior dtile/merge use of smXS done
    {
      int row = tid & 127, kh = (tid >> 7) * 64;
      int swz = ((row >> 3) & 7) << 3;
#pragma unroll
      for (int g = 0; g < 8; ++g) {
        int k0 = kh + g * 8;
        float4 a = *(const float4*)&x[(size_t)(sb + row) * Dd + k0];
        float4 b = *(const float4*)&x[(size_t)(sb + row) * Dd + k0 + 4];
        *(uint4*)&smXS[row * PXS + (k0 ^ swz)] = pk8(a, b);
      }
      if (tid < STILE) sqs_l[tid] = sq[sb + tid];
    }
    __syncthreads();
    floatx4 C[2][8];
#pragma unroll
    for (int mt = 0; mt < 2; ++mt)
#pragma unroll
      for (int nt = 0; nt < 8; ++nt)
#pragma unroll
        for (int rr = 0; rr < 4; ++rr) C[mt][nt][rr] = 0.f;
#pragma unroll
    for (int nt = 0; nt < 8; ++nt) {
      int s = nt * 16 + n15;
      int swz = ((s >> 3) & 7) << 3;
#pragma unroll
      for (int ks = 0; ks < 4; ++ks) {
        int k0 = ks * 32 + quad * 8;
        short8 bfr = *(const short8*)&smXS[s * PXS + (k0 ^ swz)];
        C[0][nt] = __builtin_amdgcn_mfma_f32_16x16x32_bf16(afr[0][ks], bfr, C[0][nt], 0, 0, 0);
        C[1][nt] = __builtin_amdgcn_mfma_f32_16x16x32_bf16(afr[1][ks], bfr, C[1][nt], 0, 0, 0);
      }
    }
    // source sq for this tile (both halves): col (nt*16+n15) in 0..127
    float sc[8];
#pragma unroll
    for (int nt = 0; nt < 8; ++nt) sc[nt] = sqs_l[nt * 16 + n15];
    __syncthreads();  // xs reads done -> alias as dtile
#pragma unroll
    for (int h = 0; h < 2; ++h) {
      if (h) __syncthreads();
      // writer computes full distance d = -2*dot + sq_i + sq_j
#pragma unroll
      for (int mt = 0; mt < 2; ++mt)
#pragma unroll
        for (int nt = 0; nt < 4; ++nt)
#pragma unroll
          for (int rr = 0; rr < 4; ++rr) {
            int row = wave * 32 + mt * 16 + quad * 4 + rr;
            int col = nt * 16 + n15;
            float d = fmaf(-2.f, C[mt][nt + 4 * h][rr], sqi8[mt * 4 + rr]) + sc[nt + 4 * h];
            dtile[row * PDD + col] = d;
          }
      __syncthreads();
      // contiguous parity scan: 8 x b128 loads of 32 own columns, min-of-4 group reject
      const float* drow = &dtile[tg * PDD];
      int cbase = sl * 32;
#pragma unroll 1
      for (int j = 0; j < 8; ++j) {
        float4 v = *(const float4*)&drow[cbase + j * 4];
        float mn = fminf(fminf(v.x, v.y), fminf(v.z, v.w));
        if (mn < bd[LDEPTH - 1]) {
          float dv0 = v.x, dv1 = v.y, dv2 = v.z, dv3 = v.w;
#pragma unroll
          for (int e = 0; e < 4; ++e) {
            float d = (e == 0) ? dv0 : (e == 1) ? dv1 : (e == 2) ? dv2 : dv3;
            if (d < bd[LDEPTH - 1]) {
              int col = cbase + j * 4 + e;
              if (bcnt < BDEPTH) {
                smBuf[bcnt * 256 + tid] = (ushort)col;
                ++bcnt;
              } else {
                ins(d, sb + h * 64 + col);  // overflow fallback (frequent only in early tiles)
              }
            }
          }
        }
      }
      // per-half flush while dtile is valid: re-read d by stored column
#pragma unroll 1
      for (int p = 0; p < BDEPTH; ++p) {
        bool act = p < bcnt;
        if (!__any(act)) break;
        if (act) {
          int col = smBuf[p * 256 + tid];
          float d = drow[col];
          ins(d, sb + h * 64 + col);
        }
      }
      bcnt = 0;
    }
  }

  // block-end: merge the two parity depth-8 lists per target -> sorted 16 per (target, split)
  __syncthreads();
#pragma unroll
  for (int o = 0; o < LDEPTH; ++o) {
    mbD[tid * LDEPTH + o] = bd[o];
    mbI[tid * LDEPTH + o] = bi[o];
  }
  __syncthreads();
  if (tid < TT) {
    const float* la = &mbD[(2 * tid) * LDEPTH];
    const float* lb = &mbD[(2 * tid + 1) * LDEPTH];
    const int* ia = &mbI[(2 * tid) * LDEPTH];
    const int* ib = &mbI[(2 * tid + 1) * LDEPTH];
    int pa = 0, pb = 0;
    size_t base = ((size_t)(tb + tid) * NSPLIT + split) * KK;
#pragma unroll
    for (int o = 0; o < KK; ++o) {
      float da = (pa < LDEPTH) ? la[pa] : 3.4e38f;
      float db = (pb < LDEPTH) ? lb[pb] : 3.4e38f;
      int iaa = (pa < LDEPTH) ? ia[pa] : 0x7fffffff;
      int ibb = (pb < LDEPTH) ? ib[pb] : 0x7fffffff;
      bool pick = (da < db) || (da == db && iaa < ibb);
      part_d[base + o] = pick ? da : db;
      part_i[base + o] = pick ? iaa : ibb;
      pa += pick ? 1 : 0;
      pb += pick ? 0 : 1;
    }
  }
}

// merge split lists -> approx top-32 candidate indices per target
__global__ void k_knn_merge(const float* __restrict__ part_d, const int* __restrict__ part_i,
                            int* __restrict__ cand) {
  int n = blockIdx.x * 256 + threadIdx.x;
  const float* pd = part_d + (size_t)n * NSPLIT * KK;
  const int* pi = part_i + (size_t)n * NSPLIT * KK;
  int pos[NSPLIT];
#pragma unroll
  for (int l = 0; l < NSPLIT; ++l) pos[l] = 0;
  for (int o = 0; o < MCAND; ++o) {
    float bestd = 3.3e38f;
    int besti = 0x7fffffff;
    int bestl = 0;
#pragma unroll
    for (int l = 0; l < NSPLIT; ++l) {
      if (pos[l] < KK) {
        float dd = pd[l * KK + pos[l]];
        int ii = pi[l * KK + pos[l]];
        if (dd < bestd || (dd == bestd && ii < besti)) { bestd = dd; besti = ii; bestl = l; }
      }
    }
    cand[(size_t)n * MCAND + o] = besti;
#pragma unroll
    for (int l = 0; l < NSPLIT; ++l) pos[l] += (l == bestl) ? 1 : 0;
  }
}

// exact fp32 rerank of 32 candidates -> ordered top-16 (same math/ties as full fp32 scan)
__global__ __launch_bounds__(256) void k_rerank(const float* __restrict__ x,
                                                const float* __restrict__ sq,
                                                const int* __restrict__ cand,
                                                int* __restrict__ knn_src) {
  int tid = threadIdx.x;
  int wave = tid >> 6, lane = tid & 63;
  int t = blockIdx.x * 4 + wave;
  int c = lane & 31, h = lane >> 5;
  int idx = cand[(size_t)t * MCAND + c];
  const float* xt = x + (size_t)t * Dd + h * 64;
  const float* xc = x + (size_t)idx * Dd + h * 64;
  float s = 0.f;
#pragma unroll
  for (int g = 0; g < 16; ++g) {
    float4 a = *(const float4*)&xt[g * 4];
    float4 b = *(const float4*)&xc[g * 4];
    s += a.x * b.x + a.y * b.y + a.z * b.z + a.w * b.w;
  }
  s += __shfl_xor(s, 32);
  float d = fmaf(-2.f, s, sq[t]) + sq[idx];
  int rank = 0;
#pragma unroll
  for (int j = 0; j < 32; ++j) {
    float dj = __shfl(d, j);
    int ij = __shfl(idx, j);
    rank += ((dj < d) || (dj == d && ij < idx)) ? 1 : 0;
  }
  if (lane < 32 && rank < KK) knn_src[t * KK + rank] = idx;
}

// ---------------- static message MLP (bf16x3 MFMA) + grouped scatter-add ----------------
__global__ __launch_bounds__(256, 3) void k_static_msg(
    const float* __restrict__ xs, const float* __restrict__ ea, const int* __restrict__ ei,
    const int* __restrict__ mode_p, const int* __restrict__ perm, const int* __restrict__ dstS,
    const uint4* __restrict__ W1p, const float* __restrict__ b1,
    const uint4* __restrict__ W2p, const float* __restrict__ b2, float* __restrict__ agg) {
  __shared__ __align__(16) ushort smH[32 * 520];
  __shared__ int dstLoc[32];
  int tid = threadIdx.x;
  int wave = tid >> 6, lane = tid & 63;
  int pb = blockIdx.x * 32;
  int mode = *mode_p;
  int r = tid & 31, q8 = tid >> 5;
  int p = pb + r;
  int e = perm[p];
  int ds = dstS[p];
  int sr = ld_src(ei, e, mode);
  if (q8 == 0) dstLoc[r] = ds;
  const float* eap = ea + (size_t)e * DEe;
  const float* xsp = xs + (size_t)sr * Dd;
  const float* xdp = xs + (size_t)ds * Dd;
#pragma unroll
  for (int it = 0; it < 6; ++it) {
    int f = q8 * 24 + it * 4;
    float4 v;
    if (f < 64) {
      v = *(const float4*)&eap[f];
    } else {
      float4 a = *(const float4*)&xsp[f - 64];
      float4 b = *(const float4*)&xdp[f - 64];
      v = make_float4(a.x - b.x, a.y - b.y, a.z - b.z, a.w - b.w);
    }
    uint2 hi, lo;
    cvt_hilo(v, &hi, &lo);
    *(uint2*)&smH[r * 392 + f] = hi;
    *(uint2*)&smH[r * 392 + 192 + f] = lo;
  }
  __syncthreads();
  floatx4 C1[2][4];
  mfma3<6, 4>(smH, 392, W1p + (size_t)wave * 4 * 12 * 64, lane, C1);
  __syncthreads();
  {
    int q = lane >> 4, n15 = lane & 15;
#pragma unroll
    for (int hm = 0; hm < 2; ++hm)
#pragma unroll
      for (int nt = 0; nt < 4; ++nt) {
        int n = wave * 64 + nt * 16 + n15;
        float bv = b1[n];
#pragma unroll
        for (int rr = 0; rr < 4; ++rr) {
          int m = hm * 16 + q * 4 + rr;
          float h = fmaxf(C1[hm][nt][rr] + bv, 0.f);
          ushort hh = f2bf(h);
          smH[m * 520 + n] = hh;
          smH[m * 520 + 256 + n] = f2bf(h - bf2f(hh));
        }
      }
  }
  __syncthreads();
  floatx4 C2[2][2];
  mfma3<8, 2>(smH, 520, W2p + (size_t)wave * 2 * 16 * 64, lane, C2);
  __syncthreads();
  float* smM = (float*)smH;
  {
    int q = lane >> 4, n15 = lane & 15;
#pragma unroll
    for (int hm = 0; hm < 2; ++hm)
#pragma unroll
      for (int nt = 0; nt < 2; ++nt) {
        int n = wave * 32 + nt * 16 + n15;
        float bv = b2[n];
#pragma unroll
        for (int rr = 0; rr < 4; ++rr) {
          int m = hm * 16 + q * 4 + rr;
          smM[m * 132 + n] = fmaxf(C2[hm][nt][rr] + bv, 0.f);
        }
      }
  }
  __syncthreads();
  int col = tid & 127, half = tid >> 7;
  int r0 = half * 16;
  float run = smM[r0 * 132 + col];
  int prevd = dstLoc[r0];
  for (int rr = 1; rr < 16; ++rr) {
    int row = r0 + rr;
    int dd2 = dstLoc[row];
    float v = smM[row * 132 + col];
    if (dd2 != prevd) {
      atomicAdd(&agg[(size_t)prevd * Dd + col], run);
      run = v;
      prevd = dd2;
    } else {
      run += v;
    }
  }
  atomicAdd(&agg[(size_t)prevd * Dd + col], run);
}

// ---------------- dynamic (kNN) message MLP (bf16x3 MFMA), atomic-free ----------------
__global__ __launch_bounds__(256, 3) void k_dyn_msg(
    const float* __restrict__ xd, const int* __restrict__ knn, const uint4* __restrict__ W1p,
    const float* __restrict__ b1, const uint4* __restrict__ W2p, const float* __restrict__ b2,
    float* __restrict__ agg) {
  __shared__ __align__(16) ushort smH[32 * 520];
  int tid = threadIdx.x;
  int wave = tid >> 6, lane = tid & 63;
  int nb2 = blockIdx.x * 2;
  int r = tid & 31, q8 = tid >> 5;
  int tgt = nb2 + (r >> 4);
  int nj = knn[tgt * KK + (r & 15)];
  const float* xip = xd + (size_t)tgt * Dd;
  const float* xjp = xd + (size_t)nj * Dd;
#pragma unroll
  for (int it = 0; it < 8; ++it) {
    int f = q8 * 32 + it * 4;
    float4 v;
    if (f < 128) {
      v = *(const float4*)&xip[f];
    } else {
      float4 a = *(const float4*)&xjp[f - 128];
      float4 b = *(const float4*)&xip[f - 128];
      v = make_float4(a.x - b.x, a.y - b.y, a.z - b.z, a.w - b.w);
    }
    uint2 hi, lo;
    cvt_hilo(v, &hi, &lo);
    *(uint2*)&smH[r * 520 + f] = hi;
    *(uint2*)&smH[r * 520 + 256 + f] = lo;
  }
  __syncthreads();
  floatx4 C1[2][4];
  mfma3<8, 4>(smH, 520, W1p + (size_t)wave * 4 * 16 * 64, lane, C1);
  __syncthreads();
  {
    int q = lane >> 4, n15 = lane & 15;
#pragma unroll
    for (int hm = 0; hm < 2; ++hm)
#pragma unroll
      for (int nt = 0; nt < 4; ++nt) {
        int n = wave * 64 + nt * 16 + n15;
        float bv = b1[n];
#pragma unroll
        for (int rr = 0; rr < 4; ++rr) {
          int m = hm * 16 + q * 4 + rr;
          float h = fmaxf(C1[hm][nt][rr] + bv, 0.f);
          ushort hh = f2bf(h);
          smH[m * 520 + n] = hh;
          smH[m * 520 + 256 + n] = f2bf(h - bf2f(hh));
        }
      }
  }
  __syncthreads();
  floatx4 C2[2][2];
  mfma3<8, 2>(smH, 520, W2p + (size_t)wave * 2 * 16 * 64, lane, C2);
  int q = lane >> 4, n15 = lane & 15;
#pragma unroll
  for (int hm = 0; hm < 2; ++hm)
#pragma unroll
    for (int nt = 0; nt < 2; ++nt) {
      int n = wave * 32 + nt * 16 + n15;
      float bv = b2[n];
      float s = 0.f;
#pragma unroll
      for (int rr = 0; rr < 4; ++rr) s += fmaxf(C2[hm][nt][rr] + bv, 0.f);
      s += __shfl_xor(s, 16);
      s += __shfl_xor(s, 32);
      if (q == 0) agg[(size_t)(nb2 + hm) * Dd + n] = s;
    }
}

// ---------------- fp32 fused 2-layer MLP core (node update / fuse) ----------------
__device__ __forceinline__ void mlp_l1(int tid, int indim, const float* __restrict__ W1,
                                       const float* __restrict__ b1, float* smA, float* smB) {
  int rg = tid >> 5, cg = tid & 31;
  float acc[32];
#pragma unroll
  for (int i = 0; i < 32; ++i) acc[i] = 0.f;
  for (int kc = 0; kc < indim / 8; ++kc) {
    const float* W1g = W1 + (size_t)kc * 8 * Hh;
    *(float4*)&smB[tid * 4] = *(const float4*)&W1g[tid * 4];
    *(float4*)&smB[1024 + tid * 4] = *(const float4*)&W1g[1024 + tid * 4];
    __syncthreads();
#pragma unroll
    for (int k = 0; k < 8; ++k) {
      int kk = kc * 8 + k;
      float4 a0 = *(const float4*)&smA[kk * 32 + rg * 4];
      float4 b0 = *(const float4*)&smB[k * Hh + cg * 8];
      float4 b1v = *(const float4*)&smB[k * Hh + cg * 8 + 4];
      float av[4] = {a0.x, a0.y, a0.z, a0.w};
      float bv[8] = {b0.x, b0.y, b0.z, b0.w, b1v.x, b1v.y, b1v.z, b1v.w};
#pragma unroll
      for (int rr = 0; rr < 4; ++rr)
#pragma unroll
        for (int cc = 0; cc < 8; ++cc) acc[rr * 8 + cc] += av[rr] * bv[cc];
    }
    __syncthreads();
  }
  float4 bb0 = *(const float4*)&b1[cg * 8];
  float4 bb1 = *(const float4*)&b1[cg * 8 + 4];
  float bs[8] = {bb0.x, bb0.y, bb0.z, bb0.w, bb1.x, bb1.y, bb1.z, bb1.w};
#pragma unroll
  for (int rr = 0; rr < 4; ++rr) {
    int row = rg * 4 + rr;
    float4 h0, h1;
    h0.x = fmaxf(acc[rr * 8 + 0] + bs[0], 0.f);
    h0.y = fmaxf(acc[rr * 8 + 1] + bs[1], 0.f);
    h0.z = fmaxf(acc[rr * 8 + 2] + bs[2], 0.f);
    h0.w = fmaxf(acc[rr * 8 + 3] + bs[3], 0.f);
    h1.x = fmaxf(acc[rr * 8 + 4] + bs[4], 0.f);
    h1.y = fmaxf(acc[rr * 8 + 5] + bs[5], 0.f);
    h1.z = fmaxf(acc[rr * 8 + 6] + bs[6], 0.f);
    h1.w = fmaxf(acc[rr * 8 + 7] + bs[7], 0.f);
    *(float4*)&smA[row * 260 + cg * 8] = h0;
    *(float4*)&smA[row * 260 + cg * 8 + 4] = h1;
  }
  __syncthreads();
}

__device__ __forceinline__ void mlp_l2(int tid, const float* __restrict__ W2,
                                       const float* smA, float* smB, float acc2[16]) {
  int rg2 = tid >> 5, cg2 = tid & 31;
#pragma unroll
  for (int i = 0; i < 16; ++i) acc2[i] = 0.f;
  for (int kc = 0; kc < Hh / 16; ++kc) {
    const float* W2g = W2 + (size_t)kc * 16 * Dd;
    *(float4*)&smB[tid * 4] = *(const float4*)&W2g[tid * 4];
    *(float4*)&smB[1024 + tid * 4] = *(const float4*)&W2g[1024 + tid * 4];
    __syncthreads();
#pragma unroll
    for (int k = 0; k < 16; ++k) {
      int kk = kc * 16 + k;
      float4 b0 = *(const float4*)&smB[k * Dd + cg2 * 4];
#pragma unroll
      for (int rr = 0; rr < 4; ++rr) {
        float a = smA[(rg2 * 4 + rr) * 260 + kk];
        acc2[rr * 4 + 0] += a * b0.x;
        acc2[rr * 4 + 1] += a * b0.y;
        acc2[rr * 4 + 2] += a * b0.z;
        acc2[rr * 4 + 3] += a * b0.w;
      }
    }
    __syncthreads();
  }
}

__global__ __launch_bounds__(256, 3) void k_node_mlp2(
    const float* __restrict__ in1, const float* __restrict__ in2, int indim,
    const float* __restrict__ W1, const float* __restrict__ b1, const float* __restrict__ W2,
    const float* __restrict__ b2, float* __restrict__ out) {
  __shared__ float smA[32 * 260];
  __shared__ float smB[2048];
  int tid = threadIdx.x;
  int nb = blockIdx.x * 32;
  int r = tid & 31, q = tid >> 5;
  for (int pass = 0; pass < indim / 32; ++pass) {
    int k0 = pass * 32 + q * 4;
    float4 v;
    if (k0 < Dd)
      v = *(const float4*)&in1[(size_t)(nb + r) * Dd + k0];
    else
      v = *(const float4*)&in2[(size_t)(nb + r) * Dd + (k0 - Dd)];
    smA[(k0 + 0) * 32 + r] = v.x;
    smA[(k0 + 1) * 32 + r] = v.y;
    smA[(k0 + 2) * 32 + r] = v.z;
    smA[(k0 + 3) * 32 + r] = v.w;
  }
  __syncthreads();
  mlp_l1(tid, indim, W1, b1, smA, smB);
  float acc2[16];
  mlp_l2(tid, W2, smA, smB, acc2);
  int rg2 = tid >> 5, cg2 = tid & 31;
  float4 ob = *(const float4*)&b2[cg2 * 4];
#pragma unroll
  for (int rr = 0; rr < 4; ++rr) {
    float4 o;
    o.x = fmaxf(acc2[rr * 4 + 0] + ob.x, 0.f);
    o.y = fmaxf(acc2[rr * 4 + 1] + ob.y, 0.f);
    o.z = fmaxf(acc2[rr * 4 + 2] + ob.z, 0.f);
    o.w = fmaxf(acc2[rr * 4 + 3] + ob.w, 0.f);
    *(float4*)&out[(size_t)(nb + rg2 * 4 + rr) * Dd + cg2 * 4] = o;
  }
}

__global__ __launch_bounds__(256) void k_refine(const float* __restrict__ ein,
                                                const float* __restrict__ rW,
                                                const float* __restrict__ rb,
                                                float* __restrict__ eout) {
  __shared__ float lea[16 * 64];
  __shared__ float ldsW[64 * 64];
  int tid = threadIdx.x;
  int eb = blockIdx.x * 16;
  *(float4*)&lea[tid * 4] = *(const float4*)&ein[(size_t)eb * DEe + tid * 4];
#pragma unroll
  for (int m = 0; m < 4; ++m) {
    int i4 = tid + m * 256;
    *(float4*)&ldsW[i4 * 4] = *(const float4*)&rW[i4 * 4];
  }
  __syncthreads();
  int j = tid & 63, eg = tid >> 6;
  float bias = rb[j];
  float acc0 = 0.f, acc1 = 0.f, acc2 = 0.f, acc3 = 0.f;
#pragma unroll 8
  for (int k = 0; k < 64; ++k) {
    float w = ldsW[k * 64 + j];
    acc0 += lea[(eg + 0) * 64 + k] * w;
    acc1 += lea[(eg + 4) * 64 + k] * w;
    acc2 += lea[(eg + 8) * 64 + k] * w;
    acc3 += lea[(eg + 12) * 64 + k] * w;
  }
  eout[(size_t)(eb + eg + 0) * DEe + j] = fmaxf(acc0 + bias, 0.f);
  eout[(size_t)(eb + eg + 4) * DEe + j] = fmaxf(acc1 + bias, 0.f);
  eout[(size_t)(eb + eg + 8) * DEe + j] = fmaxf(acc2 + bias, 0.f);
  eout[(size_t)(eb + eg + 12) * DEe + j] = fmaxf(acc3 + bias, 0.f);
}

extern "C" void kernel_launch(void* const* d_in, const int* in_sizes, int n_in, void* d_out,
                              int out_size, void* d_ws, size_t ws_size, hipStream_t stream) {
  (void)in_sizes; (void)n_in; (void)out_size; (void)ws_size;
  const float* x = (const float*)d_in[0];
  const float* edge_attr = (const float*)d_in[1];
  const float* sW1 = (const float*)d_in[2];
  const float* sb1 = (const float*)d_in[3];
  const float* sW2 = (const float*)d_in[4];
  const float* sb2 = (const float*)d_in[5];
  const float* uW1 = (const float*)d_in[6];
  const float* ub1 = (const float*)d_in[7];
  const float* uW2 = (const float*)d_in[8];
  const float* ub2 = (const float*)d_in[9];
  const float* rW = (const float*)d_in[10];
  const float* rb = (const float*)d_in[11];
  const float* dW1 = (const float*)d_in[12];
  const float* db1 = (const float*)d_in[13];
  const float* dW2 = (const float*)d_in[14];
  const float* db2 = (const float*)d_in[15];
  const float* dUW1 = (const float*)d_in[16];
  const float* dUb1 = (const float*)d_in[17];
  const float* dUW2 = (const float*)d_in[18];
  const float* dUb2 = (const float*)d_in[19];
  const float* fW1 = (const float*)d_in[20];
  const float* fb1 = (const float*)d_in[21];
  const float* fW2 = (const float*)d_in[22];
  const float* fb2 = (const float*)d_in[23];
  const int* ei = (const int*)d_in[24];
  float* out = (float*)d_out;

  float* wsf = (float*)d_ws;
  size_t off = 0;
  float* ea_ws = wsf + off; off += (size_t)Ee * DEe;
  float* xs_ws = wsf + off; off += (size_t)Nn * Dd;
  float* xd_ws = wsf + off; off += (size_t)Nn * Dd;
  float* agg = wsf + off;   off += (size_t)Nn * Dd;
  float* sq = wsf + off;    off += Nn;
  int* knn_src = (int*)(wsf + off); off += (size_t)Nn * KK;
  int* hist = (int*)(wsf + off);   off += Nn;
  int* cursor = (int*)(wsf + off); off += Nn;
  int* perm = (int*)(wsf + off);   off += Ee;
  int* dstS = (int*)(wsf + off);   off += Ee;
  int* modep = (int*)(wsf + off);  off += 1;
  off = (off + 3) & ~(size_t)3;  // 16B align for uint4
  uint4* wpk = (uint4*)(wsf + off); off += (size_t)110592 * 4;
  // kNN scratch overlaps ea_ws (edge_attr refinement dead before dynamic branch)
  float* part_d = ea_ws;
  int* part_i = (int*)(ea_ws + (size_t)Nn * NSPLIT * KK);
  int* cand = (int*)(ea_ws + 2 * (size_t)Nn * NSPLIT * KK);

  // edge_index probe + counting sort by dst
  k_detect<<<1, 64, 0, stream>>>(ei, modep);
  hipMemsetAsync(hist, 0, Nn * sizeof(int), stream);
  k_hist<<<Ee / 256, 256, 0, stream>>>(ei, modep, hist);
  k_scan<<<1, 256, 0, stream>>>(hist, cursor);
  k_scatter<<<Ee / 256, 256, 0, stream>>>(ei, modep, cursor, perm, dstS);

  // repack all msg-MLP weights into bf16 hi/lo MFMA-B layout
  k_repack<<<432, 256, 0, stream>>>(sW1, sW2, dW1, dW2, wpk);

  // ---- static branch: 3 convs + 2 refiners ----
  const float* xs_cur = x;
  const float* ea_cur = edge_attr;
  for (int i = 0; i < 3; ++i) {
    hipMemsetAsync(agg, 0, (size_t)Nn * Dd * sizeof(float), stream);
    k_static_msg<<<Ee / 32, 256, 0, stream>>>(
        xs_cur, ea_cur, ei, modep, perm, dstS, wpk + (size_t)i * 12288,
        sb1 + (size_t)i * Hh, wpk + 36864 + (size_t)i * 8192, sb2 + (size_t)i * Dd, agg);
    k_node_mlp2<<<Nn / 32, 256, 0, stream>>>(
        agg, (const float*)nullptr, Dd, uW1 + (size_t)i * Dd * Hh, ub1 + (size_t)i * Hh,
        uW2 + (size_t)i * Hh * Dd, ub2 + (size_t)i * Dd, xs_ws);
    xs_cur = xs_ws;
    if (i < 2) {
      k_refine<<<Ee / 16, 256, 0, stream>>>(ea_cur, rW + (size_t)i * DEe * DEe,
                                            rb + (size_t)i * DEe, ea_ws);
      ea_cur = ea_ws;
    }
  }

  // ---- dynamic branch: 2 kNN convs (MFMA prefilter -> merge32 -> exact rerank) ----
  const float* xd_cur = x;
  for (int i = 0; i < 2; ++i) {
    k_sq<<<Nn / 256, 256, 0, stream>>>(xd_cur, sq);
    k_knn_part<<<(Nn / TT) * NSPLIT, 256, 0, stream>>>(xd_cur, sq, part_d, part_i);
    k_knn_merge<<<Nn / 256, 256, 0, stream>>>(part_d, part_i, cand);
    k_rerank<<<Nn / 4, 256, 0, stream>>>(xd_cur, sq, cand, knn_src);
    k_dyn_msg<<<Nn / 2, 256, 0, stream>>>(
        xd_cur, knn_src, wpk + 61440 + (size_t)i * 16384, db1 + (size_t)i * Hh,
        wpk + 94208 + (size_t)i * 8192, db2 + (size_t)i * Dd, agg);
    k_node_mlp2<<<Nn / 32, 256, 0, stream>>>(
        agg, (const float*)nullptr, Dd, dUW1 + (size_t)i * Dd * Hh, dUb1 + (size_t)i * Hh,
        dUW2 + (size_t)i * Hh * Dd, dUb2 + (size_t)i * Dd, xd_ws);
    xd_cur = xd_ws;
  }

  // ---- fuse MLP ----
  k_node_mlp2<<<Nn / 32, 256, 0, stream>>>(xs_ws, xd_ws, 2 * Dd, fW1, fb1, fW2, fb2, out);
}

// Round 8
// 2805.242 us; speedup vs baseline: 1.1396x; 1.0364x over previous
//
#include <hip/hip_runtime.h>

#define Nn 16384
#define Ee 262144
#define Dd 128
#define DEe 64
#define Hh 256
#define KK 16
#define NSPLIT 16
#define TT 128      /* knn targets per block */
#define STILE 128   /* knn source tile */
#define SWEEP (Nn / NSPLIT)
#define PXS 136     /* bf16 source-tile pitch (ushorts) */
#define PDD 68      /* dtile pitch (floats); 68*4=272B = 16B-aligned rows for b128 scan */
#define MCAND 32    /* rerank candidates per target */
#define BDEPTH 8    /* per-lane survivor buffer depth */
#define LDEPTH 8    /* per-parity-thread top list depth (2x8 -> merged 16/split) */

typedef __attribute__((ext_vector_type(8))) short short8;
typedef __attribute__((ext_vector_type(4))) float floatx4;

// ---------- bf16 helpers ----------
__device__ __forceinline__ ushort f2bf(float f) {
  uint u = __float_as_uint(f);
  u += 0x7fffu + ((u >> 16) & 1u);
  return (ushort)(u >> 16);
}
__device__ __forceinline__ float bf2f(ushort h) { return __uint_as_float(((uint)h) << 16); }
__device__ __forceinline__ void cvt_hilo(float4 v, uint2* hi, uint2* lo) {
  ushort h0 = f2bf(v.x), h1 = f2bf(v.y), h2 = f2bf(v.z), h3 = f2bf(v.w);
  ushort l0 = f2bf(v.x - bf2f(h0)), l1 = f2bf(v.y - bf2f(h1));
  ushort l2 = f2bf(v.z - bf2f(h2)), l3 = f2bf(v.w - bf2f(h3));
  hi->x = (uint)h0 | ((uint)h1 << 16); hi->y = (uint)h2 | ((uint)h3 << 16);
  lo->x = (uint)l0 | ((uint)l1 << 16); lo->y = (uint)l2 | ((uint)l3 << 16);
}
__device__ __forceinline__ uint4 pk8(float4 a, float4 b) {
  uint4 o;
  o.x = (uint)f2bf(a.x) | ((uint)f2bf(a.y) << 16);
  o.y = (uint)f2bf(a.z) | ((uint)f2bf(a.w) << 16);
  o.z = (uint)f2bf(b.x) | ((uint)f2bf(b.y) << 16);
  o.w = (uint)f2bf(b.z) | ((uint)f2bf(b.w) << 16);
  return o;
}

// edge_index access: mode=1 -> int32 layout, mode=0 -> int64 (low words at even positions)
__device__ __forceinline__ int ld_src(const int* ei, int e, int mode) {
  return mode ? ei[e] : ei[2 * e];
}
__device__ __forceinline__ int ld_dst(const int* ei, int e, int mode) {
  return mode ? ei[Ee + e] : ei[2 * Ee + 2 * e];
}

__global__ void k_detect(const int* __restrict__ ei, int* __restrict__ flag) {
  if (blockIdx.x == 0 && threadIdx.x == 0) {
    int any = 0;
    for (int i = 0; i < 64; ++i) any |= ei[2 * i + 1];
    *flag = (any != 0) ? 1 : 0;
  }
}

__global__ void k_hist(const int* __restrict__ ei, const int* __restrict__ mode_p,
                       int* __restrict__ hist) {
  int e = blockIdx.x * 256 + threadIdx.x;
  int mode = *mode_p;
  atomicAdd(&hist[ld_dst(ei, e, mode)], 1);
}

__global__ void k_scan(const int* __restrict__ hist, int* __restrict__ cursor) {
  __shared__ int part[256];
  __shared__ int partx[256];
  int t = threadIdx.x;
  int base = t * (Nn / 256);
  int s = 0;
  for (int i = 0; i < Nn / 256; ++i) s += hist[base + i];
  part[t] = s;
  __syncthreads();
  if (t == 0) {
    int run = 0;
    for (int i = 0; i < 256; ++i) { partx[i] = run; run += part[i]; }
  }
  __syncthreads();
  int run = partx[t];
  for (int i = 0; i < Nn / 256; ++i) { int v = hist[base + i]; cursor[base + i] = run; run += v; }
}

__global__ void k_scatter(const int* __restrict__ ei, const int* __restrict__ mode_p,
                          int* __restrict__ cursor, int* __restrict__ perm,
                          int* __restrict__ dstS) {
  int e = blockIdx.x * 256 + threadIdx.x;
  int mode = *mode_p;
  int d = ld_dst(ei, e, mode);
  int pos = atomicAdd(&cursor[d], 1);
  perm[pos] = e;
  dstS[pos] = d;
}

// squared norms (exact same accumulation order as before) + bf16 copy of x (same f2bf bits)
__global__ void k_sq(const float* __restrict__ x, float* __restrict__ sq,
                     ushort* __restrict__ xbf) {
  int n = blockIdx.x * 256 + threadIdx.x;
  const float4* p = (const float4*)(x + (size_t)n * Dd);
  uint4* ob = (uint4*)(xbf + (size_t)n * Dd);
  float acc = 0.f;
#pragma unroll
  for (int i = 0; i < Dd / 8; ++i) {
    float4 v = p[2 * i];
    acc += v.x * v.x + v.y * v.y + v.z * v.z + v.w * v.w;
    float4 w = p[2 * i + 1];
    acc += w.x * w.x + w.y * w.y + w.z * w.z + w.w * w.w;
    ob[i] = pk8(v, w);
  }
  sq[n] = acc;
}

// ---- weight repack: fp32 [K][N] -> bf16 MFMA-B layout, K' = 2K (hi rows then lo rows) ----
__global__ void k_repack(const float* __restrict__ sW1, const float* __restrict__ sW2,
                         const float* __restrict__ dW1, const float* __restrict__ dW2,
                         uint4* __restrict__ out) {
  int gid = blockIdx.x * 256 + threadIdx.x;
  const float* W; int K, N, u, obase;
  if (gid < 36864) {
    int i = gid / 12288; u = gid - i * 12288;
    W = sW1 + (size_t)i * 49152; K = 192; N = 256; obase = i * 12288;
  } else if (gid < 61440) {
    int g = gid - 36864; int i = g / 8192; u = g - i * 8192;
    W = sW2 + (size_t)i * 32768; K = 256; N = 128; obase = 36864 + i * 8192;
  } else if (gid < 94208) {
    int g = gid - 61440; int i = g / 16384; u = g - i * 16384;
    W = dW1 + (size_t)i * 65536; K = 256; N = 256; obase = 61440 + i * 16384;
  } else if (gid < 110592) {
    int g = gid - 94208; int i = g / 8192; u = g - i * 8192;
    W = dW2 + (size_t)i * 32768; K = 256; N = 128; obase = 94208 + i * 8192;
  } else return;
  int lane = u & 63;
  int t = u >> 6;
  int ksteps = K / 16;
  int kstep = t % ksteps, ntile = t / ksteps;
  int R = K / 32;
  bool lo = kstep >= R;
  int k0 = (lo ? kstep - R : kstep) * 32 + (lane >> 4) * 8;
  int n = ntile * 16 + (lane & 15);
  ushort v[8];
#pragma unroll
  for (int j = 0; j < 8; ++j) {
    float w = W[(size_t)(k0 + j) * N + n];
    ushort h = f2bf(w);
    v[j] = lo ? f2bf(w - bf2f(h)) : h;
  }
  uint4 o;
  o.x = (uint)v[0] | ((uint)v[1] << 16);
  o.y = (uint)v[2] | ((uint)v[3] << 16);
  o.z = (uint)v[4] | ((uint)v[5] << 16);
  o.w = (uint)v[6] | ((uint)v[7] << 16);
  out[obase + u] = o;
}

// ---- bf16x3 MFMA GEMM core for MLPs ----
template <int RK, int NT>
__device__ __forceinline__ void mfma3(const ushort* aB, int pitch, const uint4* __restrict__ Wp,
                                      int lane, floatx4 C[2][NT]) {
  int q = lane >> 4, m0 = lane & 15;
  short8 ahc[RK][2];
#pragma unroll
  for (int hm = 0; hm < 2; ++hm)
#pragma unroll
    for (int nt = 0; nt < NT; ++nt)
#pragma unroll
      for (int rr = 0; rr < 4; ++rr) C[hm][nt][rr] = 0.f;
#pragma unroll
  for (int s = 0; s < RK; ++s) {
    short8 ah0 = *(const short8*)(aB + m0 * pitch + s * 32 + q * 8);
    short8 ah1 = *(const short8*)(aB + (m0 + 16) * pitch + s * 32 + q * 8);
    short8 al0 = *(const short8*)(aB + m0 * pitch + (RK + s) * 32 + q * 8);
    short8 al1 = *(const short8*)(aB + (m0 + 16) * pitch + (RK + s) * 32 + q * 8);
    ahc[s][0] = ah0;
    ahc[s][1] = ah1;
#pragma unroll
    for (int nt = 0; nt < NT; ++nt) {
      uint4 bw = Wp[(nt * 2 * RK + s) * 64 + lane];
      short8 b = *(short8*)&bw;
      C[0][nt] = __builtin_amdgcn_mfma_f32_16x16x32_bf16(ah0, b, C[0][nt], 0, 0, 0);
      C[1][nt] = __builtin_amdgcn_mfma_f32_16x16x32_bf16(ah1, b, C[1][nt], 0, 0, 0);
      C[0][nt] = __builtin_amdgcn_mfma_f32_16x16x32_bf16(al0, b, C[0][nt], 0, 0, 0);
      C[1][nt] = __builtin_amdgcn_mfma_f32_16x16x32_bf16(al1, b, C[1][nt], 0, 0, 0);
    }
  }
#pragma unroll
  for (int s = 0; s < RK; ++s) {
#pragma unroll
    for (int nt = 0; nt < NT; ++nt) {
      uint4 bw = Wp[(nt * 2 * RK + RK + s) * 64 + lane];
      short8 b = *(short8*)&bw;
      C[0][nt] = __builtin_amdgcn_mfma_f32_16x16x32_bf16(ahc[s][0], b, C[0][nt], 0, 0, 0);
      C[1][nt] = __builtin_amdgcn_mfma_f32_16x16x32_bf16(ahc[s][1], b, C[1][nt], 0, 0, 0);
    }
  }
}

// ---- kNN prefilter: precomputed bf16 staging, writer-side distances, float4 scan ----
__global__ __launch_bounds__(256, 3) void k_knn_part(const ushort* __restrict__ xbf,
                                                     const float* __restrict__ sq,
                                                     float* __restrict__ part_d,
                                                     int* __restrict__ part_i) {
  __shared__ __align__(16) ushort smXS[128 * PXS];  // bf16 src tile / fp32 dtile / merge bufs
  __shared__ float sqs_l[STILE];
  __shared__ ushort smBuf[BDEPTH * 256];  // survivor col buffer, [p][tid]
  float* dtile = (float*)smXS;            // [128][PDD], holds full distances d
  float* mbD = (float*)smXS;              // merge: 256*LDEPTH floats
  int* mbI = ((int*)smXS) + 2048;
  int tid = threadIdx.x;
  int wave = tid >> 6, lane = tid & 63;
  int quad = lane >> 4, n15 = lane & 15;
  int tileT = blockIdx.x >> 4;
  int split = blockIdx.x & 15;
  int tb = tileT * TT;
  int tg = tid >> 1, sl = tid & 1;

  // per-lane C-row target sq (8 output rows: mt in {0,1}, rr in 0..3)
  float sqi8[8];
#pragma unroll
  for (int mt = 0; mt < 2; ++mt)
#pragma unroll
    for (int rr = 0; rr < 4; ++rr)
      sqi8[mt * 4 + rr] = sq[tb + wave * 32 + mt * 16 + quad * 4 + rr];

  // A-fragments straight from precomputed bf16 (identical f2bf bits)
  short8 afr[2][4];
#pragma unroll
  for (int mt = 0; mt < 2; ++mt) {
    int row = tb + wave * 32 + mt * 16 + n15;
#pragma unroll
    for (int ks = 0; ks < 4; ++ks)
      afr[mt][ks] = *(const short8*)&xbf[(size_t)row * Dd + ks * 32 + quad * 8];
  }

  float bd[LDEPTH];
  int bi[LDEPTH];
#pragma unroll
  for (int p2 = 0; p2 < LDEPTH; ++p2) { bd[p2] = 3.0e38f; bi[p2] = 0x7fffffff; }
  int bcnt = 0;

  // exact depth-8 predicated sorted insert
  auto ins = [&](float d, int gidx) {
#pragma unroll
    for (int p = LDEPTH - 1; p >= 1; --p) {
      bool shift = d < bd[p - 1];
      bool here = (!shift) && (d < bd[p]);
      float nb = shift ? bd[p - 1] : (here ? d : bd[p]);
      int ni = shift ? bi[p - 1] : (here ? gidx : bi[p]);
      bd[p] = nb;
      bi[p] = ni;
    }
    if (d < bd[0]) { bd[0] = d; bi[0] = gidx; }
  };

#pragma unroll 1
  for (int st = 0; st < SWEEP / STILE; ++st) {
    int sb = split * SWEEP + st * STILE;
    __syncthreads();  // prior dtile/merge use of smXS done
    {
      int row = tid & 127, kh = (tid >> 7) * 64;
      int swz = ((row >> 3) & 7) << 3;
      const ushort* src = &xbf[(size_t)(sb + row) * Dd + kh];
#pragma unroll
      for (int g = 0; g < 8; ++g) {
        int k0 = kh + g * 8;
        *(uint4*)&smXS[row * PXS + (k0 ^ swz)] = *(const uint4*)&src[g * 8];
      }
      if (tid < STILE) sqs_l[tid] = sq[sb + tid];
    }
    __syncthreads();
    floatx4 C[2][8];
#pragma unroll
    for (int mt = 0; mt < 2; ++mt)
#pragma unroll
      for (int nt = 0; nt < 8; ++nt)
#pragma unroll
        for (int rr = 0; rr < 4; ++rr) C[mt][nt][rr] = 0.f;
#pragma unroll
    for (int nt = 0; nt < 8; ++nt) {
      int s = nt * 16 + n15;
      int swz = ((s >> 3) & 7) << 3;
#pragma unroll
      for (int ks = 0; ks < 4; ++ks) {
        int k0 = ks * 32 + quad * 8;
        short8 bfr = *(const short8*)&smXS[s * PXS + (k0 ^ swz)];
        C[0][nt] = __builtin_amdgcn_mfma_f32_16x16x32_bf16(afr[0][ks], bfr, C[0][nt], 0, 0, 0);
        C[1][nt] = __builtin_amdgcn_mfma_f32_16x16x32_bf16(afr[1][ks], bfr, C[1][nt], 0, 0, 0);
      }
    }
    // source sq for this tile (both halves): col (nt*16+n15) in 0..127
    float sc[8];
#pragma unroll
    for (int nt = 0; nt < 8; ++nt) sc[nt] = sqs_l[nt * 16 + n15];
    __syncthreads();  // xs reads done -> alias as dtile
#pragma unroll
    for (int h = 0; h < 2; ++h) {
      if (h) __syncthreads();
      // writer computes full distance d = -2*dot + sq_i + sq_j
#pragma unroll
      for (int mt = 0; mt < 2; ++mt)
#pragma unroll
        for (int nt = 0; nt < 4; ++nt)
#pragma unroll
          for (int rr = 0; rr < 4; ++rr) {
            int row = wave * 32 + mt * 16 + quad * 4 + rr;
            int col = nt * 16 + n15;
            float d = fmaf(-2.f, C[mt][nt + 4 * h][rr], sqi8[mt * 4 + rr]) + sc[nt + 4 * h];
            dtile[row * PDD + col] = d;
          }
      __syncthreads();
      // contiguous parity scan: 8 x b128 loads of 32 own columns, min-of-4 group reject
      const float* drow = &dtile[tg * PDD];
      int cbase = sl * 32;
#pragma unroll 1
      for (int j = 0; j < 8; ++j) {
        float4 v = *(const float4*)&drow[cbase + j * 4];
        float mn = fminf(fminf(v.x, v.y), fminf(v.z, v.w));
        if (mn < bd[LDEPTH - 1]) {
          float dv0 = v.x, dv1 = v.y, dv2 = v.z, dv3 = v.w;
#pragma unroll
          for (int e = 0; e < 4; ++e) {
            float d = (e == 0) ? dv0 : (e == 1) ? dv1 : (e == 2) ? dv2 : dv3;
            if (d < bd[LDEPTH - 1]) {
              int col = cbase + j * 4 + e;
              if (bcnt < BDEPTH) {
                smBuf[bcnt * 256 + tid] = (ushort)col;
                ++bcnt;
              } else {
                ins(d, sb + h * 64 + col);  // overflow fallback (frequent only in early tiles)
              }
            }
          }
        }
      }
      // per-half flush while dtile is valid: re-read d by stored column
#pragma unroll 1
      for (int p = 0; p < BDEPTH; ++p) {
        bool act = p < bcnt;
        if (!__any(act)) break;
        if (act) {
          int col = smBuf[p * 256 + tid];
          float d = drow[col];
          ins(d, sb + h * 64 + col);
        }
      }
      bcnt = 0;
    }
  }

  // block-end: merge the two parity depth-8 lists per target -> sorted 16 per (target, split)
  __syncthreads();
#pragma unroll
  for (int o = 0; o < LDEPTH; ++o) {
    mbD[tid * LDEPTH + o] = bd[o];
    mbI[tid * LDEPTH + o] = bi[o];
  }
  __syncthreads();
  if (tid < TT) {
    const float* la = &mbD[(2 * tid) * LDEPTH];
    const float* lb = &mbD[(2 * tid + 1) * LDEPTH];
    const int* ia = &mbI[(2 * tid) * LDEPTH];
    const int* ib = &mbI[(2 * tid + 1) * LDEPTH];
    int pa = 0, pb = 0;
    size_t base = ((size_t)(tb + tid) * NSPLIT + split) * KK;
#pragma unroll
    for (int o = 0; o < KK; ++o) {
      float da = (pa < LDEPTH) ? la[pa] : 3.4e38f;
      float db = (pb < LDEPTH) ? lb[pb] : 3.4e38f;
      int iaa = (pa < LDEPTH) ? ia[pa] : 0x7fffffff;
      int ibb = (pb < LDEPTH) ? ib[pb] : 0x7fffffff;
      bool pick = (da < db) || (da == db && iaa < ibb);
      part_d[base + o] = pick ? da : db;
      part_i[base + o] = pick ? iaa : ibb;
      pa += pick ? 1 : 0;
      pb += pick ? 0 : 1;
    }
  }
}

// merge split lists -> approx top-32 candidate indices per target
__global__ void k_knn_merge(const float* __restrict__ part_d, const int* __restrict__ part_i,
                            int* __restrict__ cand) {
  int n = blockIdx.x * 256 + threadIdx.x;
  const float* pd = part_d + (size_t)n * NSPLIT * KK;
  const int* pi = part_i + (size_t)n * NSPLIT * KK;
  int pos[NSPLIT];
#pragma unroll
  for (int l = 0; l < NSPLIT; ++l) pos[l] = 0;
  for (int o = 0; o < MCAND; ++o) {
    float bestd = 3.3e38f;
    int besti = 0x7fffffff;
    int bestl = 0;
#pragma unroll
    for (int l = 0; l < NSPLIT; ++l) {
      if (pos[l] < KK) {
        float dd = pd[l * KK + pos[l]];
        int ii = pi[l * KK + pos[l]];
        if (dd < bestd || (dd == bestd && ii < besti)) { bestd = dd; besti = ii; bestl = l; }
      }
    }
    cand[(size_t)n * MCAND + o] = besti;
#pragma unroll
    for (int l = 0; l < NSPLIT; ++l) pos[l] += (l == bestl) ? 1 : 0;
  }
}

// exact fp32 rerank of 32 candidates -> ordered top-16 (same math/ties as full fp32 scan)
__global__ __launch_bounds__(256) void k_rerank(const float* __restrict__ x,
                                                const float* __restrict__ sq,
                                                const int* __restrict__ cand,
                                                int* __restrict__ knn_src) {
  int tid = threadIdx.x;
  int wave = tid >> 6, lane = tid & 63;
  int t = blockIdx.x * 4 + wave;
  int c = lane & 31, h = lane >> 5;
  int idx = cand[(size_t)t * MCAND + c];
  const float* xt = x + (size_t)t * Dd + h * 64;
  const float* xc = x + (size_t)idx * Dd + h * 64;
  float s = 0.f;
#pragma unroll
  for (int g = 0; g < 16; ++g) {
    float4 a = *(const float4*)&xt[g * 4];
    float4 b = *(const float4*)&xc[g * 4];
    s += a.x * b.x + a.y * b.y + a.z * b.z + a.w * b.w;
  }
  s += __shfl_xor(s, 32);
  float d = fmaf(-2.f, s, sq[t]) + sq[idx];
  int rank = 0;
#pragma unroll
  for (int j = 0; j < 32; ++j) {
    float dj = __shfl(d, j);
    int ij = __shfl(idx, j);
    rank += ((dj < d) || (dj == d && ij < idx)) ? 1 : 0;
  }
  if (lane < 32 && rank < KK) knn_src[t * KK + rank] = idx;
}

// ---------------- static message MLP (bf16x3 MFMA) + grouped scatter-add ----------------
__global__ __launch_bounds__(256, 3) void k_static_msg(
    const float* __restrict__ xs, const float* __restrict__ ea, const int* __restrict__ ei,
    const int* __restrict__ mode_p, const int* __restrict__ perm, const int* __restrict__ dstS,
    const uint4* __restrict__ W1p, const float* __restrict__ b1,
    const uint4* __restrict__ W2p, const float* __restrict__ b2, float* __restrict__ agg) {
  __shared__ __align__(16) ushort smH[32 * 520];
  __shared__ int dstLoc[32];
  int tid = threadIdx.x;
  int wave = tid >> 6, lane = tid & 63;
  int pb = blockIdx.x * 32;
  int mode = *mode_p;
  int r = tid & 31, q8 = tid >> 5;
  int p = pb + r;
  int e = perm[p];
  int ds = dstS[p];
  int sr = ld_src(ei, e, mode);
  if (q8 == 0) dstLoc[r] = ds;
  const float* eap = ea + (size_t)e * DEe;
  const float* xsp = xs + (size_t)sr * Dd;
  const float* xdp = xs + (size_t)ds * Dd;
#pragma unroll
  for (int it = 0; it < 6; ++it) {
    int f = q8 * 24 + it * 4;
    float4 v;
    if (f < 64) {
      v = *(const float4*)&eap[f];
    } else {
      float4 a = *(const float4*)&xsp[f - 64];
      float4 b = *(const float4*)&xdp[f - 64];
      v = make_float4(a.x - b.x, a.y - b.y, a.z - b.z, a.w - b.w);
    }
    uint2 hi, lo;
    cvt_hilo(v, &hi, &lo);
    *(uint2*)&smH[r * 392 + f] = hi;
    *(uint2*)&smH[r * 392 + 192 + f] = lo;
  }
  __syncthreads();
  floatx4 C1[2][4];
  mfma3<6, 4>(smH, 392, W1p + (size_t)wave * 4 * 12 * 64, lane, C1);
  __syncthreads();
  {
    int q = lane >> 4, n15 = lane & 15;
#pragma unroll
    for (int hm = 0; hm < 2; ++hm)
#pragma unroll
      for (int nt = 0; nt < 4; ++nt) {
        int n = wave * 64 + nt * 16 + n15;
        float bv = b1[n];
#pragma unroll
        for (int rr = 0; rr < 4; ++rr) {
          int m = hm * 16 + q * 4 + rr;
          float h = fmaxf(C1[hm][nt][rr] + bv, 0.f);
          ushort hh = f2bf(h);
          smH[m * 520 + n] = hh;
          smH[m * 520 + 256 + n] = f2bf(h - bf2f(hh));
        }
      }
  }
  __syncthreads();
  floatx4 C2[2][2];
  mfma3<8, 2>(smH, 520, W2p + (size_t)wave * 2 * 16 * 64, lane, C2);
  __syncthreads();
  float* smM = (float*)smH;
  {
    int q = lane >> 4, n15 = lane & 15;
#pragma unroll
    for (int hm = 0; hm < 2; ++hm)
#pragma unroll
      for (int nt = 0; nt < 2; ++nt) {
        int n = wave * 32 + nt * 16 + n15;
        float bv = b2[n];
#pragma unroll
        for (int rr = 0; rr < 4; ++rr) {
          int m = hm * 16 + q * 4 + rr;
          smM[m * 132 + n] = fmaxf(C2[hm][nt][rr] + bv, 0.f);
        }
      }
  }
  __syncthreads();
  int col = tid & 127, half = tid >> 7;
  int r0 = half * 16;
  float run = smM[r0 * 132 + col];
  int prevd = dstLoc[r0];
  for (int rr = 1; rr < 16; ++rr) {
    int row = r0 + rr;
    int dd2 = dstLoc[row];
    float v = smM[row * 132 + col];
    if (dd2 != prevd) {
      atomicAdd(&agg[(size_t)prevd * Dd + col], run);
      run = v;
      prevd = dd2;
    } else {
      run += v;
    }
  }
  atomicAdd(&agg[(size_t)prevd * Dd + col], run);
}

// ---------------- dynamic (kNN) message MLP (bf16x3 MFMA), atomic-free ----------------
__global__ __launch_bounds__(256, 3) void k_dyn_msg(
    const float* __restrict__ xd, const int* __restrict__ knn, const uint4* __restrict__ W1p,
    const float* __restrict__ b1, const uint4* __restrict__ W2p, const float* __restrict__ b2,
    float* __restrict__ agg) {
  __shared__ __align__(16) ushort smH[32 * 520];
  int tid = threadIdx.x;
  int wave = tid >> 6, lane = tid & 63;
  int nb2 = blockIdx.x * 2;
  int r = tid & 31, q8 = tid >> 5;
  int tgt = nb2 + (r >> 4);
  int nj = knn[tgt * KK + (r & 15)];
  const float* xip = xd + (size_t)tgt * Dd;
  const float* xjp = xd + (size_t)nj * Dd;
#pragma unroll
  for (int it = 0; it < 8; ++it) {
    int f = q8 * 32 + it * 4;
    float4 v;
    if (f < 128) {
      v = *(const float4*)&xip[f];
    } else {
      float4 a = *(const float4*)&xjp[f - 128];
      float4 b = *(const float4*)&xip[f - 128];
      v = make_float4(a.x - b.x, a.y - b.y, a.z - b.z, a.w - b.w);
    }
    uint2 hi, lo;
    cvt_hilo(v, &hi, &lo);
    *(uint2*)&smH[r * 520 + f] = hi;
    *(uint2*)&smH[r * 520 + 256 + f] = lo;
  }
  __syncthreads();
  floatx4 C1[2][4];
  mfma3<8, 4>(smH, 520, W1p + (size_t)wave * 4 * 16 * 64, lane, C1);
  __syncthreads();
  {
    int q = lane >> 4, n15 = lane & 15;
#pragma unroll
    for (int hm = 0; hm < 2; ++hm)
#pragma unroll
      for (int nt = 0; nt < 4; ++nt) {
        int n = wave * 64 + nt * 16 + n15;
        float bv = b1[n];
#pragma unroll
        for (int rr = 0; rr < 4; ++rr) {
          int m = hm * 16 + q * 4 + rr;
          float h = fmaxf(C1[hm][nt][rr] + bv, 0.f);
          ushort hh = f2bf(h);
          smH[m * 520 + n] = hh;
          smH[m * 520 + 256 + n] = f2bf(h - bf2f(hh));
        }
      }
  }
  __syncthreads();
  floatx4 C2[2][2];
  mfma3<8, 2>(smH, 520, W2p + (size_t)wave * 2 * 16 * 64, lane, C2);
  int q = lane >> 4, n15 = lane & 15;
#pragma unroll
  for (int hm = 0; hm < 2; ++hm)
#pragma unroll
    for (int nt = 0; nt < 2; ++nt) {
      int n = wave * 32 + nt * 16 + n15;
      float bv = b2[n];
      float s = 0.f;
#pragma unroll
      for (int rr = 0; rr < 4; ++rr) s += fmaxf(C2[hm][nt][rr] + bv, 0.f);
      s += __shfl_xor(s, 16);
      s += __shfl_xor(s, 32);
      if (q == 0) agg[(size_t)(nb2 + hm) * Dd + n] = s;
    }
}

// ---------------- fp32 fused 2-layer MLP core (node update / fuse) ----------------
__device__ __forceinline__ void mlp_l1(int tid, int indim, const float* __restrict__ W1,
                                       const float* __restrict__ b1, float* smA, float* smB) {
  int rg = tid >> 5, cg = tid & 31;
  float acc[32];
#pragma unroll
  for (int i = 0; i < 32; ++i) acc[i] = 0.f;
  for (int kc = 0; kc < indim / 8; ++kc) {
    const float* W1g = W1 + (size_t)kc * 8 * Hh;
    *(float4*)&smB[tid * 4] = *(const float4*)&W1g[tid * 4];
    *(float4*)&smB[1024 + tid * 4] = *(const float4*)&W1g[1024 + tid * 4];
    __syncthreads();
#pragma unroll
    for (int k = 0; k < 8; ++k) {
      int kk = kc * 8 + k;
      float4 a0 = *(const float4*)&smA[kk * 32 + rg * 4];
      float4 b0 = *(const float4*)&smB[k * Hh + cg * 8];
      float4 b1v = *(const float4*)&smB[k * Hh + cg * 8 + 4];
      float av[4] = {a0.x, a0.y, a0.z, a0.w};
      float bv[8] = {b0.x, b0.y, b0.z, b0.w, b1v.x, b1v.y, b1v.z, b1v.w};
#pragma unroll
      for (int rr = 0; rr < 4; ++rr)
#pragma unroll
        for (int cc = 0; cc < 8; ++cc) acc[rr * 8 + cc] += av[rr] * bv[cc];
    }
    __syncthreads();
  }
  float4 bb0 = *(const float4*)&b1[cg * 8];
  float4 bb1 = *(const float4*)&b1[cg * 8 + 4];
  float bs[8] = {bb0.x, bb0.y, bb0.z, bb0.w, bb1.x, bb1.y, bb1.z, bb1.w};
#pragma unroll
  for (int rr = 0; rr < 4; ++rr) {
    int row = rg * 4 + rr;
    float4 h0, h1;
    h0.x = fmaxf(acc[rr * 8 + 0] + bs[0], 0.f);
    h0.y = fmaxf(acc[rr * 8 + 1] + bs[1], 0.f);
    h0.z = fmaxf(acc[rr * 8 + 2] + bs[2], 0.f);
    h0.w = fmaxf(acc[rr * 8 + 3] + bs[3], 0.f);
    h1.x = fmaxf(acc[rr * 8 + 4] + bs[4], 0.f);
    h1.y = fmaxf(acc[rr * 8 + 5] + bs[5], 0.f);
    h1.z = fmaxf(acc[rr * 8 + 6] + bs[6], 0.f);
    h1.w = fmaxf(acc[rr * 8 + 7] + bs[7], 0.f);
    *(float4*)&smA[row * 260 + cg * 8] = h0;
    *(float4*)&smA[row * 260 + cg * 8 + 4] = h1;
  }
  __syncthreads();
}

__device__ __forceinline__ void mlp_l2(int tid, const float* __restrict__ W2,
                                       const float* smA, float* smB, float acc2[16]) {
  int rg2 = tid >> 5, cg2 = tid & 31;
#pragma unroll
  for (int i = 0; i < 16; ++i) acc2[i] = 0.f;
  for (int kc = 0; kc < Hh / 16; ++kc) {
    const float* W2g = W2 + (size_t)kc * 16 * Dd;
    *(float4*)&smB[tid * 4] = *(const float4*)&W2g[tid * 4];
    *(float4*)&smB[1024 + tid * 4] = *(const float4*)&W2g[1024 + tid * 4];
    __syncthreads();
#pragma unroll
    for (int k = 0; k < 16; ++k) {
      int kk = kc * 16 + k;
      float4 b0 = *(const float4*)&smB[k * Dd + cg2 * 4];
#pragma unroll
      for (int rr = 0; rr < 4; ++rr) {
        float a = smA[(rg2 * 4 + rr) * 260 + kk];
        acc2[rr * 4 + 0] += a * b0.x;
        acc2[rr * 4 + 1] += a * b0.y;
        acc2[rr * 4 + 2] += a * b0.z;
        acc2[rr * 4 + 3] += a * b0.w;
      }
    }
    __syncthreads();
  }
}

__global__ __launch_bounds__(256, 3) void k_node_mlp2(
    const float* __restrict__ in1, const float* __restrict__ in2, int indim,
    const float* __restrict__ W1, const float* __restrict__ b1, const float* __restrict__ W2,
    const float* __restrict__ b2, float* __restrict__ out) {
  __shared__ float smA[32 * 260];
  __shared__ float smB[2048];
  int tid = threadIdx.x;
  int nb = blockIdx.x * 32;
  int r = tid & 31, q = tid >> 5;
  for (int pass = 0; pass < indim / 32; ++pass) {
    int k0 = pass * 32 + q * 4;
    float4 v;
    if (k0 < Dd)
      v = *(const float4*)&in1[(size_t)(nb + r) * Dd + k0];
    else
      v = *(const float4*)&in2[(size_t)(nb + r) * Dd + (k0 - Dd)];
    smA[(k0 + 0) * 32 + r] = v.x;
    smA[(k0 + 1) * 32 + r] = v.y;
    smA[(k0 + 2) * 32 + r] = v.z;
    smA[(k0 + 3) * 32 + r] = v.w;
  }
  __syncthreads();
  mlp_l1(tid, indim, W1, b1, smA, smB);
  float acc2[16];
  mlp_l2(tid, W2, smA, smB, acc2);
  int rg2 = tid >> 5, cg2 = tid & 31;
  float4 ob = *(const float4*)&b2[cg2 * 4];
#pragma unroll
  for (int rr = 0; rr < 4; ++rr) {
    float4 o;
    o.x = fmaxf(acc2[rr * 4 + 0] + ob.x, 0.f);
    o.y = fmaxf(acc2[rr * 4 + 1] + ob.y, 0.f);
    o.z = fmaxf(acc2[rr * 4 + 2] + ob.z, 0.f);
    o.w = fmaxf(acc2[rr * 4 + 3] + ob.w, 0.f);
    *(float4*)&out[(size_t)(nb + rg2 * 4 + rr) * Dd + cg2 * 4] = o;
  }
}

__global__ __launch_bounds__(256) void k_refine(const float* __restrict__ ein,
                                                const float* __restrict__ rW,
                                                const float* __restrict__ rb,
                                                float* __restrict__ eout) {
  __shared__ float lea[16 * 64];
  __shared__ float ldsW[64 * 64];
  int tid = threadIdx.x;
  int eb = blockIdx.x * 16;
  *(float4*)&lea[tid * 4] = *(const float4*)&ein[(size_t)eb * DEe + tid * 4];
#pragma unroll
  for (int m = 0; m < 4; ++m) {
    int i4 = tid + m * 256;
    *(float4*)&ldsW[i4 * 4] = *(const float4*)&rW[i4 * 4];
  }
  __syncthreads();
  int j = tid & 63, eg = tid >> 6;
  float bias = rb[j];
  float acc0 = 0.f, acc1 = 0.f, acc2 = 0.f, acc3 = 0.f;
#pragma unroll 8
  for (int k = 0; k < 64; ++k) {
    float w = ldsW[k * 64 + j];
    acc0 += lea[(eg + 0) * 64 + k] * w;
    acc1 += lea[(eg + 4) * 64 + k] * w;
    acc2 += lea[(eg + 8) * 64 + k] * w;
    acc3 += lea[(eg + 12) * 64 + k] * w;
  }
  eout[(size_t)(eb + eg + 0) * DEe + j] = fmaxf(acc0 + bias, 0.f);
  eout[(size_t)(eb + eg + 4) * DEe + j] = fmaxf(acc1 + bias, 0.f);
  eout[(size_t)(eb + eg + 8) * DEe + j] = fmaxf(acc2 + bias, 0.f);
  eout[(size_t)(eb + eg + 12) * DEe + j] = fmaxf(acc3 + bias, 0.f);
}

extern "C" void kernel_launch(void* const* d_in, const int* in_sizes, int n_in, void* d_out,
                              int out_size, void* d_ws, size_t ws_size, hipStream_t stream) {
  (void)in_sizes; (void)n_in; (void)out_size; (void)ws_size;
  const float* x = (const float*)d_in[0];
  const float* edge_attr = (const float*)d_in[1];
  const float* sW1 = (const float*)d_in[2];
  const float* sb1 = (const float*)d_in[3];
  const float* sW2 = (const float*)d_in[4];
  const float* sb2 = (const float*)d_in[5];
  const float* uW1 = (const float*)d_in[6];
  const float* ub1 = (const float*)d_in[7];
  const float* uW2 = (const float*)d_in[8];
  const float* ub2 = (const float*)d_in[9];
  const float* rW = (const float*)d_in[10];
  const float* rb = (const float*)d_in[11];
  const float* dW1 = (const float*)d_in[12];
  const float* db1 = (const float*)d_in[13];
  const float* dW2 = (const float*)d_in[14];
  const float* db2 = (const float*)d_in[15];
  const float* dUW1 = (const float*)d_in[16];
  const float* dUb1 = (const float*)d_in[17];
  const float* dUW2 = (const float*)d_in[18];
  const float* dUb2 = (const float*)d_in[19];
  const float* fW1 = (const float*)d_in[20];
  const float* fb1 = (const float*)d_in[21];
  const float* fW2 = (const float*)d_in[22];
  const float* fb2 = (const float*)d_in[23];
  const int* ei = (const int*)d_in[24];
  float* out = (float*)d_out;

  float* wsf = (float*)d_ws;
  size_t off = 0;
  float* ea_ws = wsf + off; off += (size_t)Ee * DEe;
  float* xs_ws = wsf + off; off += (size_t)Nn * Dd;
  float* xd_ws = wsf + off; off += (size_t)Nn * Dd;
  float* agg = wsf + off;   off += (size_t)Nn * Dd;
  float* sq = wsf + off;    off += Nn;
  int* knn_src = (int*)(wsf + off); off += (size_t)Nn * KK;
  int* hist = (int*)(wsf + off);   off += Nn;
  int* cursor = (int*)(wsf + off); off += Nn;
  int* perm = (int*)(wsf + off);   off += Ee;
  int* dstS = (int*)(wsf + off);   off += Ee;
  int* modep = (int*)(wsf + off);  off += 1;
  off = (off + 3) & ~(size_t)3;  // 16B align for uint4
  uint4* wpk = (uint4*)(wsf + off); off += (size_t)110592 * 4;
  ushort* xbf = (ushort*)(wsf + off); off += (size_t)Nn * Dd / 2;  // bf16 copy of current x
  // kNN scratch overlaps ea_ws (edge_attr refinement dead before dynamic branch)
  float* part_d = ea_ws;
  int* part_i = (int*)(ea_ws + (size_t)Nn * NSPLIT * KK);
  int* cand = (int*)(ea_ws + 2 * (size_t)Nn * NSPLIT * KK);

  // edge_index probe + counting sort by dst
  k_detect<<<1, 64, 0, stream>>>(ei, modep);
  hipMemsetAsync(hist, 0, Nn * sizeof(int), stream);
  k_hist<<<Ee / 256, 256, 0, stream>>>(ei, modep, hist);
  k_scan<<<1, 256, 0, stream>>>(hist, cursor);
  k_scatter<<<Ee / 256, 256, 0, stream>>>(ei, modep, cursor, perm, dstS);

  // repack all msg-MLP weights into bf16 hi/lo MFMA-B layout
  k_repack<<<432, 256, 0, stream>>>(sW1, sW2, dW1, dW2, wpk);

  // ---- static branch: 3 convs + 2 refiners ----
  const float* xs_cur = x;
  const float* ea_cur = edge_attr;
  for (int i = 0; i < 3; ++i) {
    hipMemsetAsync(agg, 0, (size_t)Nn * Dd * sizeof(float), stream);
    k_static_msg<<<Ee / 32, 256, 0, stream>>>(
        xs_cur, ea_cur, ei, modep, perm, dstS, wpk + (size_t)i * 12288,
        sb1 + (size_t)i * Hh, wpk + 36864 + (size_t)i * 8192, sb2 + (size_t)i * Dd, agg);
    k_node_mlp2<<<Nn / 32, 256, 0, stream>>>(
        agg, (const float*)nullptr, Dd, uW1 + (size_t)i * Dd * Hh, ub1 + (size_t)i * Hh,
        uW2 + (size_t)i * Hh * Dd, ub2 + (size_t)i * Dd, xs_ws);
    xs_cur = xs_ws;
    if (i < 2) {
      k_refine<<<Ee / 16, 256, 0, stream>>>(ea_cur, rW + (size_t)i * DEe * DEe,
                                            rb + (size_t)i * DEe, ea_ws);
      ea_cur = ea_ws;
    }
  }

  // ---- dynamic branch: 2 kNN convs (MFMA prefilter -> merge32 -> exact rerank) ----
  const float* xd_cur = x;
  for (int i = 0; i < 2; ++i) {
    k_sq<<<Nn / 256, 256, 0, stream>>>(xd_cur, sq, xbf);
    k_knn_part<<<(Nn / TT) * NSPLIT, 256, 0, stream>>>(xbf, sq, part_d, part_i);
    k_knn_merge<<<Nn / 256, 256, 0, stream>>>(part_d, part_i, cand);
    k_rerank<<<Nn / 4, 256, 0, stream>>>(xd_cur, sq, cand, knn_src);
    k_dyn_msg<<<Nn / 2, 256, 0, stream>>>(
        xd_cur, knn_src, wpk + 61440 + (size_t)i * 16384, db1 + (size_t)i * Hh,
        wpk + 94208 + (size_t)i * 8192, db2 + (size_t)i * Dd, agg);
    k_node_mlp2<<<Nn / 32, 256, 0, stream>>>(
        agg, (const float*)nullptr, Dd, dUW1 + (size_t)i * Dd * Hh, dUb1 + (size_t)i * Hh,
        dUW2 + (size_t)i * Hh * Dd, dUb2 + (size_t)i * Dd, xd_ws);
    xd_cur = xd_ws;
  }

  // ---- fuse MLP ----
  k_node_mlp2<<<Nn / 32, 256, 0, stream>>>(xs_ws, xd_ws, 2 * Dd, fW1, fb1, fW2, fb2, out);
}